// Round 8
// baseline (229.773 us; speedup 1.0000x reference)
//
#include <hip/hip_runtime.h>
#include <hip/hip_bf16.h>

// TGCN fused pipeline for MI355X (gfx950).
//  * A = softmax(pre*mask) = c_n*1^T + sparse(10/row)  ->  all graph convs are
//    O(N*TOPK*C) via colsum + 10-term gathers. No N^3 anywhere.
//  * Exact Threefry-2x32 replication of jax.random.uniform(key(42)) noise so
//    top-k tie-breaks match the reference bit-for-bit (verified r1-r7).
//  * pre = relu(s_b*(a+at_b)), s_b>=1  =>  pre-order == a-order; per-node
//    candidate hoisting + LDS rank-select (verified r4-r7).
// R8 (r7 fusion gave only -5us: k_topk was 2 blocks/CU, 12 barriers):
//  * k_topk: 2048 blocks x 256 thr, 1 node/block, 3 barriers. Candidate
//    bound+compaction by warp0 only (was 8x redundant), shared via LDS.
//    Batch loop barrier-free (per-warp LDS slices, same-wave DS ordering).
//  * csx computed fully in k_pre (r2-verified colsum order); partX removed.
//  * csy via 8 partial buffers (atomic chains 2048->256); k_v sums 8 parts.

constexpr int BS = 16, NN_ = 2048, CIN = 32, OUT = 64, TK = 10;
constexpr int ROWS = BS * NN_;

// ---------------- Threefry-2x32 (matches jax._src.prng) ----------------
__device__ __forceinline__ void tf2x32(unsigned x0, unsigned x1,
                                       unsigned& o0, unsigned& o1) {
  const unsigned k0 = 0u, k1 = 42u;
  const unsigned ks2 = k0 ^ k1 ^ 0x1BD11BDAu;
#define TF_R(rot) { x0 += x1; x1 = (x1 << rot) | (x1 >> (32 - rot)); x1 ^= x0; }
  x0 += k0; x1 += k1;
  TF_R(13) TF_R(15) TF_R(26) TF_R(6)
  x0 += k1; x1 += ks2 + 1u;
  TF_R(17) TF_R(29) TF_R(16) TF_R(24)
  x0 += ks2; x1 += k0 + 2u;
  TF_R(13) TF_R(15) TF_R(26) TF_R(6)
  x0 += k0; x1 += k1 + 3u;
  TF_R(17) TF_R(29) TF_R(16) TF_R(24)
  x0 += k1; x1 += ks2 + 4u;
  TF_R(13) TF_R(15) TF_R(26) TF_R(6)
  x0 += ks2; x1 += k0 + 5u;
#undef TF_R
  o0 = x0; o1 = x1;
}

__device__ __forceinline__ float noise_val(unsigned flat) {
  unsigned o0, o1; tf2x32(0u, flat, o0, o1);
  unsigned bits = o0 ^ o1;
  float u = __uint_as_float((bits >> 9) | 0x3f800000u) - 1.0f;
  return 0.01f * u;
}

// ---------------- K_pre: Wn + Wt + csx (full) + csy_part zero ----------------
// [0,768): Wn[n][ki][o] = sum_d ne[n,d] wp[d,ki,o]
// [768,864): Wt[b][ki][o] = sum_d n_t[b,d] wp[10+d,ki,o]
// [864,880): csx[b][c] = colsum_m x[b,m,c]  (r2-verified order, double accum)
// 880: zero csy_part[8][512]
__global__ __launch_bounds__(256) void k_pre(const float* __restrict__ ne,
                                             const float* __restrict__ n_t,
                                             const float* __restrict__ wp,
                                             const float* __restrict__ x,
                                             float* __restrict__ Wn,
                                             float* __restrict__ Wt,
                                             float* __restrict__ csx,
                                             float* __restrict__ csy_part) {
  const int bid = blockIdx.x;
  __shared__ float neS[16][10];
  __shared__ double red[8][32];

  if (bid < 768) {
    const int ng = bid / 6, sg = bid % 6;
    const int slot = sg * 256 + threadIdx.x;      // 1536 slots = 96 ki x 16 o4
    const int ki = slot >> 4, o4 = slot & 15;

    if (threadIdx.x < 160)
      neS[threadIdx.x / 10][threadIdx.x % 10] =
          ne[(ng * 16 + threadIdx.x / 10) * 10 + threadIdx.x % 10];

    const float4* wp4 = (const float4*)wp;
    float4 w[10];
    #pragma unroll
    for (int d = 0; d < 10; ++d) w[d] = wp4[(d * 96 + ki) * 16 + o4];
    __syncthreads();

    float4* Wn4 = (float4*)Wn;
    #pragma unroll 4
    for (int nn = 0; nn < 16; ++nn) {
      float4 acc = {0.f, 0.f, 0.f, 0.f};
      #pragma unroll
      for (int d = 0; d < 10; ++d) {
        float e = neS[nn][d];
        acc.x = fmaf(e, w[d].x, acc.x); acc.y = fmaf(e, w[d].y, acc.y);
        acc.z = fmaf(e, w[d].z, acc.z); acc.w = fmaf(e, w[d].w, acc.w);
      }
      Wn4[((size_t)(ng * 16 + nn) * 96 + ki) * 16 + o4] = acc;
    }
  } else if (bid < 864) {
    int gid = (bid - 768) * 256 + threadIdx.x;    // 24576 = 16*96*16
    int b = gid / 1536, rem = gid % 1536, ki = rem >> 4, o4 = rem & 15;
    const float4* wp4 = (const float4*)wp;
    float4 acc = {0.f, 0.f, 0.f, 0.f};
    #pragma unroll
    for (int d = 0; d < 8; ++d) {
      float e = n_t[b * 8 + d];
      float4 w = wp4[((10 + d) * 96 + ki) * 16 + o4];
      acc.x = fmaf(e, w.x, acc.x); acc.y = fmaf(e, w.y, acc.y);
      acc.z = fmaf(e, w.z, acc.z); acc.w = fmaf(e, w.w, acc.w);
    }
    ((float4*)Wt)[(b * 96 + ki) * 16 + o4] = acc;
  } else if (bid < 880) {
    const int b = bid - 864;
    const int c = threadIdx.x & 31, g = threadIdx.x >> 5;
    double acc = 0.0;
    for (int m = g; m < 2048; m += 8)
      acc += (double)x[(((b << 11) + m) << 5) + c];
    red[g][c] = acc;
    __syncthreads();
    if (g == 0) {
      double s2 = red[0][c];
      #pragma unroll
      for (int i = 1; i < 8; ++i) s2 += red[i][c];
      csx[(b << 5) + c] = (float)s2;
    }
  } else {
    #pragma unroll
    for (int i = 0; i < 16; ++i) csy_part[i * 256 + threadIdx.x] = 0.f;
  }
}

// ---------------- K_topk: A0 row + top-k + Y1 + csy partials ----------------
// 2048 blocks x 256 thr; 1 node/block; warp w -> batches [w*4, w*4+4).
__global__ __launch_bounds__(256, 6) void k_topk(const float* __restrict__ ne,
                                                 const float* __restrict__ t,
                                                 const float* __restrict__ n_t,
                                                 const float* __restrict__ p,
                                                 const float* __restrict__ x,
                                                 const float* __restrict__ csx,
                                                 float* __restrict__ cinv,
                                                 int* __restrict__ idxb,
                                                 float* __restrict__ wgt,
                                                 float* __restrict__ Y1,
                                                 float* __restrict__ csy_part) {
  const int n = blockIdx.x;
  const int warp = threadIdx.x >> 6, lane = threadIdx.x & 63;

  __shared__ float rowS[2048];                    // 8 KiB
  __shared__ float neN[10];
  __shared__ float candA[128];
  __shared__ int   candM[128];
  __shared__ int   Cs;
  __shared__ unsigned long long keyS[4][128];     // 4 KiB, per-warp slices
  __shared__ int   winI[16][10];                  // per-batch winners
  __shared__ float winW[16][10];
  __shared__ float ciS[16];

  if (threadIdx.x < 10) neN[threadIdx.x] = ne[n * 10 + threadIdx.x];
  __syncthreads();                                // BAR0: neN

  // ---- phase 1: rowS[m] = ne[n]·ne[m] (bit-identical fmaf order) ----
  #pragma unroll
  for (int g2 = 0; g2 < 2; ++g2) {
    const int m0 = g2 * 1024 + threadIdx.x * 4;
    float nm[40];
    const float4* nf = (const float4*)(ne + (size_t)m0 * 10);
    #pragma unroll
    for (int i = 0; i < 10; ++i) {
      float4 q = nf[i];
      nm[i * 4 + 0] = q.x; nm[i * 4 + 1] = q.y;
      nm[i * 4 + 2] = q.z; nm[i * 4 + 3] = q.w;
    }
    float res[4];
    #pragma unroll
    for (int rr = 0; rr < 4; ++rr) {
      float acc = 0.f;
      #pragma unroll
      for (int d = 0; d < 10; ++d)
        acc = fmaf(neN[d], nm[rr * 10 + d], acc);
      res[rr] = acc;
    }
    *(float4*)&rowS[m0] = make_float4(res[0], res[1], res[2], res[3]);
  }
  __syncthreads();                                // BAR1: rowS complete

  // ---- warp0: 11th-distinct-lane-max bound + candidate compaction ----
  if (warp == 0) {
    float lm = -3.4e38f;
    #pragma unroll
    for (int j = 0; j < 8; ++j) {
      float4 f = ((const float4*)rowS)[j * 64 + lane];
      lm = fmaxf(lm, fmaxf(fmaxf(f.x, f.y), fmaxf(f.z, f.w)));
    }
    float last = 3.4e38f;
    for (int rd = 0; rd < 11; ++rd) {
      float x2 = (lm < last) ? lm : -3.4e38f;
      #pragma unroll
      for (int off = 32; off > 0; off >>= 1) x2 = fmaxf(x2, __shfl_xor(x2, off));
      last = x2;
    }
    const float T = last - 0.0101f;               // a-space margin (s_b >= 1)

    int cnt = 0;
    #pragma unroll
    for (int slot = 0; slot < 32; ++slot) {
      float v = rowS[(slot >> 2) * 256 + lane * 4 + (slot & 3)];
      bool c = (v >= T);
      unsigned long long mk = __ballot(c);
      if (c) {
        int pos = cnt + __popcll(mk & ((1ull << lane) - 1ull));
        if (pos < 128) {
          candA[pos] = v;
          candM[pos] = ((slot >> 2) << 8) + (lane << 2) + (slot & 3);
        }
      }
      cnt += (int)__popcll(mk);
    }
    if (lane == 0) Cs = cnt < 128 ? cnt : 128;
  }
  __syncthreads();                                // BAR2: candidates shared

  const int C = Cs;
  const bool two = (C > 64);
  float a0c = 0.f, a1c = 0.f; int m0c = 0, m1c = 0;
  if (lane < C) { a0c = candA[lane]; m0c = candM[lane]; }
  if (two && lane + 64 < C) { a1c = candA[lane + 64]; m1c = candM[lane + 64]; }

  // ---- per-batch selection (barrier-free: per-warp slices, wave-ordered) ----
  for (int bi = 0; bi < 4; ++bi) {
    const int b = warp * 4 + bi;
    const int r = (b << 11) | n;

    float at = 0.f;
    #pragma unroll
    for (int d = 0; d < 8; ++d) at = fmaf(n_t[b * 8 + d], t[b * 8 + d], at);
    const float s = 1.0f + 0.3f * (1.0f / (1.0f + expf(-p[b])));

    float pre0 = fmaxf(s * (a0c + at), 0.f);
    unsigned long long k0 = 0ull;
    if (lane < C) {
      float key0 = pre0 + noise_val((unsigned)r * 2048u + (unsigned)m0c);
      k0 = ((unsigned long long)__float_as_uint(key0) << 32) |
           (unsigned)(2047 - m0c);
      keyS[warp][lane] = k0;
    }
    float pre1 = 0.f;
    unsigned long long k1 = 0ull;
    if (two) {
      if (lane + 64 < C) {
        pre1 = fmaxf(s * (a1c + at), 0.f);
        float key1 = pre1 + noise_val((unsigned)r * 2048u + (unsigned)m1c);
        k1 = ((unsigned long long)__float_as_uint(key1) << 32) |
             (unsigned)(2047 - m1c);
      }
      keyS[warp][lane + 64] = k1;
    }

    int rank0 = 0, rank1 = 0;
    for (int j2 = 0; j2 < C; ++j2) {
      unsigned long long kj = keyS[warp][j2];
      rank0 += (kj > k0) ? 1 : 0;
      if (two) rank1 += (kj > k1) ? 1 : 0;
    }
    bool w0 = (lane < C) && (rank0 < 10);
    bool w1 = two && (lane + 64 < C) && (rank1 < 10);

    float e0 = w0 ? expf(pre0) : 0.f;
    float e1 = w1 ? expf(pre1) : 0.f;
    float sum = e0 + e1;
    #pragma unroll
    for (int off = 32; off > 0; off >>= 1) sum += __shfl_xor(sum, off);
    const float ci = 1.0f / (2038.0f + sum);

    unsigned long long mk0 = __ballot(w0);
    if (w0) {
      int pos = __popcll(mk0 & ((1ull << lane) - 1ull));
      idxb[r * 10 + pos] = m0c;
      wgt[r * 10 + pos] = (e0 - 1.0f) * ci;
      winI[b][pos] = m0c;
      winW[b][pos] = (e0 - 1.0f) * ci;
    }
    if (two) {
      unsigned long long mk1 = __ballot(w1);
      int base = __popcll(mk0);
      if (w1) {
        int pos = base + __popcll(mk1 & ((1ull << lane) - 1ull));
        idxb[r * 10 + pos] = m1c;
        wgt[r * 10 + pos] = (e1 - 1.0f) * ci;
        winI[b][pos] = m1c;
        winW[b][pos] = (e1 - 1.0f) * ci;
      }
    }
    if (lane == 0) { cinv[r] = ci; ciS[b] = ci; }
  }

  // ---- Y1 phase (fused axpy): 2 passes x (2 rows x 32 cols) per warp ----
  #pragma unroll
  for (int pass = 0; pass < 2; ++pass) {
    const int bi2 = pass * 2 + (lane >> 5);
    const int b = warp * 4 + bi2;
    const int c = lane & 31;
    const int r = (b << 11) | n;
    float acc = ciS[b] * csx[(b << 5) + c];
    #pragma unroll
    for (int j = 0; j < 10; ++j) {
      int m = winI[b][j];
      float w = winW[b][j];
      acc = fmaf(w, x[(((b << 11) + m) << 5) + c], acc);
    }
    Y1[(size_t)r * 32 + c] = acc;
    atomicAdd(&csy_part[((n & 7) << 9) + (b << 5) + c], acc);
  }
}

// ---------------- K_v: Y2 = A@Y1 ; build V = [x, Y1, 2*Y2 - x] ----------------
__global__ __launch_bounds__(256) void k_v(const float* __restrict__ x,
                                           const float* __restrict__ Y1,
                                           const float* __restrict__ cinv,
                                           const int* __restrict__ idxb,
                                           const float* __restrict__ wgt,
                                           const float* __restrict__ csy_part,
                                           float* __restrict__ V) {
  int gid = blockIdx.x * 256 + threadIdx.x;
  int r = gid >> 5, c = gid & 31, b = r >> 11;
  float cs = 0.f;
  #pragma unroll
  for (int k = 0; k < 8; ++k) cs += csy_part[(k << 9) + (b << 5) + c];
  float y2 = cinv[r] * cs;
  #pragma unroll
  for (int j = 0; j < 10; ++j)
    y2 = fmaf(wgt[r * 10 + j], Y1[(((b << 11) + idxb[r * 10 + j]) << 5) + c], y2);
  float xv = x[gid], y1v = Y1[gid];
  V[r * 96 + c] = xv;
  V[r * 96 + 32 + c] = y1v;
  V[r * 96 + 64 + c] = 2.f * y2 - xv;
}

// ---------------- K_outn: node-term + bias, streaming Wn (1 node/block) ----------------
__global__ __launch_bounds__(256) void k_outn(const float* __restrict__ ne,
                                              const float* __restrict__ n_t,
                                              const float* __restrict__ Wn,
                                              const float* __restrict__ bp,
                                              const float* __restrict__ V,
                                              float* __restrict__ out) {
  const int n = blockIdx.x;                     // 2048 blocks
  __shared__ float Vs[16][100];
  __shared__ float bNs[64];

  for (int e = threadIdx.x; e < 384; e += 256) {
    int b = e / 24, j4 = e % 24;
    float4 f = *(const float4*)&V[((size_t)(b << 11) + n) * 96 + j4 * 4];
    *(float4*)&Vs[b][j4 * 4] = f;
  }
  if (threadIdx.x < 64) {
    float acc = 0.f;
    #pragma unroll
    for (int d = 0; d < 10; ++d)
      acc = fmaf(ne[n * 10 + d], bp[d * 64 + threadIdx.x], acc);
    bNs[threadIdx.x] = acc;
  }
  __syncthreads();

  const int b = threadIdx.x >> 4, og = threadIdx.x & 15;
  const float4* Wr = (const float4*)(Wn + (size_t)n * 6144);

  float4 acc = {0.f, 0.f, 0.f, 0.f};
  #pragma unroll 4
  for (int ki = 0; ki < 96; ++ki) {
    float4 wv = Wr[ki * 16 + og];
    float v = Vs[b][ki];
    acc.x = fmaf(v, wv.x, acc.x); acc.y = fmaf(v, wv.y, acc.y);
    acc.z = fmaf(v, wv.z, acc.z); acc.w = fmaf(v, wv.w, acc.w);
  }

  float4 res;
  #pragma unroll
  for (int q = 0; q < 4; ++q) {
    int o = og * 4 + q;
    float bT = 0.f;
    #pragma unroll
    for (int d = 0; d < 8; ++d)
      bT = fmaf(n_t[b * 8 + d], bp[(10 + d) * 64 + o], bT);
    (&res.x)[q] = (&acc.x)[q] + bNs[o] + bT;
  }
  *(float4*)&out[((size_t)(b << 11) + n) * 64 + og * 4] = res;
}

// ---------------- K_outt: out += V @ Wt[b] (Wt precomputed) ----------------
__global__ __launch_bounds__(512) void k_outt(const float* __restrict__ WtG,
                                              const float* __restrict__ V,
                                              float* __restrict__ out) {
  const int b = blockIdx.x >> 5, tile = blockIdx.x & 31;   // 512 blocks
  __shared__ float Wt[96][64];
  {
    const float4* src = (const float4*)(WtG + (size_t)b * 6144);
    float4* dst = (float4*)Wt;
    for (int e = threadIdx.x; e < 1536; e += 512) dst[e] = src[e];
  }
  __syncthreads();
  const int wave = threadIdx.x >> 6, lane = threadIdx.x & 63;
  const int og = lane & 15, rg = lane >> 4;
  const int r0 = tile * 64 + wave * 8 + rg * 2;

  float acc[2][4] = {};
  for (int ki4 = 0; ki4 < 24; ++ki4) {
    float4 vv[2];
    #pragma unroll
    for (int i = 0; i < 2; ++i)
      vv[i] = *(const float4*)&V[(size_t)((b << 11) + r0 + i) * 96 + ki4 * 4];
    #pragma unroll
    for (int t2 = 0; t2 < 4; ++t2) {
      float4 wv = *(const float4*)&Wt[ki4 * 4 + t2][og * 4];
      #pragma unroll
      for (int i = 0; i < 2; ++i) {
        float vi = (t2 == 0) ? vv[i].x : (t2 == 1) ? vv[i].y
                 : (t2 == 2) ? vv[i].z : vv[i].w;
        acc[i][0] = fmaf(vi, wv.x, acc[i][0]);
        acc[i][1] = fmaf(vi, wv.y, acc[i][1]);
        acc[i][2] = fmaf(vi, wv.z, acc[i][2]);
        acc[i][3] = fmaf(vi, wv.w, acc[i][3]);
      }
    }
  }
  #pragma unroll
  for (int i = 0; i < 2; ++i) {
    size_t oidx = (size_t)((b << 11) + r0 + i) * 64 + og * 4;
    float4 cur = *(float4*)&out[oidx];
    cur.x += acc[i][0]; cur.y += acc[i][1];
    cur.z += acc[i][2]; cur.w += acc[i][3];
    *(float4*)&out[oidx] = cur;
  }
}

extern "C" void kernel_launch(void* const* d_in, const int* in_sizes, int n_in,
                              void* d_out, int out_size, void* d_ws, size_t ws_size,
                              hipStream_t stream) {
  const float* x   = (const float*)d_in[0];
  const float* ne  = (const float*)d_in[1];
  const float* t   = (const float*)d_in[2];
  const float* n_t = (const float*)d_in[3];
  const float* p   = (const float*)d_in[4];
  const float* wp  = (const float*)d_in[5];
  const float* bp  = (const float*)d_in[6];
  float* out = (float*)d_out;
  float* ws = (float*)d_ws;
  (void)in_sizes; (void)n_in; (void)out_size; (void)ws_size;

  // layout (floats; ws is 268 MB)
  float* cinv     = ws;                         // 32,768
  int*   idxb     = (int*)(cinv + 32768);       // 327,680
  float* wgt      = (float*)(idxb + 327680);    // 327,680
  float* csy_part = wgt + 327680;               // 4,096 (8 partials x 512)
  float* csx      = csy_part + 4096;            // 512
  float* Y1       = csx + 512;                  // 1,048,576
  float* V        = Y1 + 1048576;               // 3,145,728
  float* Wt       = V + 3145728;                // 98,304
  float* Wn       = Wt + 98304;                 // 12,582,912

  k_pre  <<<881, 256, 0, stream>>>(ne, n_t, wp, x, Wn, Wt, csx, csy_part);
  k_topk <<<2048, 256, 0, stream>>>(ne, t, n_t, p, x, csx,
                                    cinv, idxb, wgt, Y1, csy_part);
  k_v    <<<4096, 256, 0, stream>>>(x, Y1, cinv, idxb, wgt, csy_part, V);
  k_outn <<<2048, 256, 0, stream>>>(ne, n_t, Wn, bp, V, out);
  k_outt <<<512, 512, 0, stream>>>(Wt, V, out);
}

// Round 9
// 182.037 us; speedup vs baseline: 1.2622x; 1.2622x over previous
//
#include <hip/hip_runtime.h>
#include <hip/hip_bf16.h>

// TGCN fused pipeline for MI355X (gfx950).
//  * A = softmax(pre*mask) = c_n*1^T + sparse(10/row)  ->  all graph convs are
//    O(N*TOPK*C) via colsum + 10-term gathers. No N^3 anywhere.
//  * Exact Threefry-2x32 replication of jax.random.uniform(key(42)) noise so
//    top-k tie-breaks match the reference bit-for-bit (verified r1-r8).
//  * pre = relu(s_b*(a+at_b)), s_b>=1  =>  pre-order == a-order; per-node
//    candidate hoisting + LDS rank-select (verified r4-r8).
// R9 (r8 REGRESSED: csx as 16 monolithic colsum blocks made k_pre ~110us,
//     16 CUs at 4% occupancy, serial double-chain):
//  * csx back to r7-verified 256-block chunked partX (double partials);
//    finalize to csL[512] in k_topk LDS by warps 1-3 CONCURRENT with warp0's
//    candidate compaction (same ch=0..15 order -> bit-identical).
//  * Keep r8's wins: 2048-block 3-barrier k_topk + fused Y1 + csy 8-way
//    partials; k_v sums 8 partials.

constexpr int BS = 16, NN_ = 2048, CIN = 32, OUT = 64, TK = 10;
constexpr int ROWS = BS * NN_;

// ---------------- Threefry-2x32 (matches jax._src.prng) ----------------
__device__ __forceinline__ void tf2x32(unsigned x0, unsigned x1,
                                       unsigned& o0, unsigned& o1) {
  const unsigned k0 = 0u, k1 = 42u;
  const unsigned ks2 = k0 ^ k1 ^ 0x1BD11BDAu;
#define TF_R(rot) { x0 += x1; x1 = (x1 << rot) | (x1 >> (32 - rot)); x1 ^= x0; }
  x0 += k0; x1 += k1;
  TF_R(13) TF_R(15) TF_R(26) TF_R(6)
  x0 += k1; x1 += ks2 + 1u;
  TF_R(17) TF_R(29) TF_R(16) TF_R(24)
  x0 += ks2; x1 += k0 + 2u;
  TF_R(13) TF_R(15) TF_R(26) TF_R(6)
  x0 += k0; x1 += k1 + 3u;
  TF_R(17) TF_R(29) TF_R(16) TF_R(24)
  x0 += k1; x1 += ks2 + 4u;
  TF_R(13) TF_R(15) TF_R(26) TF_R(6)
  x0 += ks2; x1 += k0 + 5u;
#undef TF_R
  o0 = x0; o1 = x1;
}

__device__ __forceinline__ float noise_val(unsigned flat) {
  unsigned o0, o1; tf2x32(0u, flat, o0, o1);
  unsigned bits = o0 ^ o1;
  float u = __uint_as_float((bits >> 9) | 0x3f800000u) - 1.0f;
  return 0.01f * u;
}

// ---------------- K_pre: Wn + Wt + partX (chunked) + csy_part zero ----------------
// [0,768): Wn[n][ki][o] = sum_d ne[n,d] wp[d,ki,o]
// [768,864): Wt[b][ki][o] = sum_d n_t[b,d] wp[10+d,ki,o]
// [864,1120): partX[b][ch][c] = partial colsum of x rows [ch*128,(ch+1)*128)
// 1120: zero csy_part[8][512]
__global__ __launch_bounds__(256) void k_pre(const float* __restrict__ ne,
                                             const float* __restrict__ n_t,
                                             const float* __restrict__ wp,
                                             const float* __restrict__ x,
                                             float* __restrict__ Wn,
                                             float* __restrict__ Wt,
                                             double* __restrict__ partX,
                                             float* __restrict__ csy_part) {
  const int bid = blockIdx.x;
  __shared__ float neS[16][10];
  __shared__ double red[8][32];

  if (bid < 768) {
    const int ng = bid / 6, sg = bid % 6;
    const int slot = sg * 256 + threadIdx.x;      // 1536 slots = 96 ki x 16 o4
    const int ki = slot >> 4, o4 = slot & 15;

    if (threadIdx.x < 160)
      neS[threadIdx.x / 10][threadIdx.x % 10] =
          ne[(ng * 16 + threadIdx.x / 10) * 10 + threadIdx.x % 10];

    const float4* wp4 = (const float4*)wp;
    float4 w[10];
    #pragma unroll
    for (int d = 0; d < 10; ++d) w[d] = wp4[(d * 96 + ki) * 16 + o4];
    __syncthreads();

    float4* Wn4 = (float4*)Wn;
    #pragma unroll 4
    for (int nn = 0; nn < 16; ++nn) {
      float4 acc = {0.f, 0.f, 0.f, 0.f};
      #pragma unroll
      for (int d = 0; d < 10; ++d) {
        float e = neS[nn][d];
        acc.x = fmaf(e, w[d].x, acc.x); acc.y = fmaf(e, w[d].y, acc.y);
        acc.z = fmaf(e, w[d].z, acc.z); acc.w = fmaf(e, w[d].w, acc.w);
      }
      Wn4[((size_t)(ng * 16 + nn) * 96 + ki) * 16 + o4] = acc;
    }
  } else if (bid < 864) {
    int gid = (bid - 768) * 256 + threadIdx.x;    // 24576 = 16*96*16
    int b = gid / 1536, rem = gid % 1536, ki = rem >> 4, o4 = rem & 15;
    const float4* wp4 = (const float4*)wp;
    float4 acc = {0.f, 0.f, 0.f, 0.f};
    #pragma unroll
    for (int d = 0; d < 8; ++d) {
      float e = n_t[b * 8 + d];
      float4 w = wp4[((10 + d) * 96 + ki) * 16 + o4];
      acc.x = fmaf(e, w.x, acc.x); acc.y = fmaf(e, w.y, acc.y);
      acc.z = fmaf(e, w.z, acc.z); acc.w = fmaf(e, w.w, acc.w);
    }
    ((float4*)Wt)[(b * 96 + ki) * 16 + o4] = acc;
  } else if (bid < 1120) {
    const int bb = bid - 864;
    const int b = bb >> 4, ch = bb & 15;
    const int c = threadIdx.x & 31, g = threadIdx.x >> 5;
    double acc = 0.0;
    for (int m = ch * 128 + g; m < ch * 128 + 128; m += 8)
      acc += (double)x[(((b << 11) + m) << 5) + c];
    red[g][c] = acc;
    __syncthreads();
    if (g == 0) {
      double s2 = red[0][c];
      #pragma unroll
      for (int i = 1; i < 8; ++i) s2 += red[i][c];
      partX[(((b << 4) + ch) << 5) + c] = s2;
    }
  } else {
    #pragma unroll
    for (int i = 0; i < 16; ++i) csy_part[i * 256 + threadIdx.x] = 0.f;
  }
}

// ---------------- K_topk: A0 row + top-k + Y1 + csy partials ----------------
// 2048 blocks x 256 thr; 1 node/block; warp w -> batches [w*4, w*4+4).
__global__ __launch_bounds__(256, 6) void k_topk(const float* __restrict__ ne,
                                                 const float* __restrict__ t,
                                                 const float* __restrict__ n_t,
                                                 const float* __restrict__ p,
                                                 const float* __restrict__ x,
                                                 const double* __restrict__ partX,
                                                 float* __restrict__ cinv,
                                                 int* __restrict__ idxb,
                                                 float* __restrict__ wgt,
                                                 float* __restrict__ Y1,
                                                 float* __restrict__ csy_part) {
  const int n = blockIdx.x;
  const int warp = threadIdx.x >> 6, lane = threadIdx.x & 63;

  __shared__ float rowS[2048];                    // 8 KiB
  __shared__ float neN[10];
  __shared__ float candA[128];
  __shared__ int   candM[128];
  __shared__ int   Cs;
  __shared__ unsigned long long keyS[4][128];     // 4 KiB, per-warp slices
  __shared__ int   winI[16][10];                  // per-batch winners
  __shared__ float winW[16][10];
  __shared__ float ciS[16];
  __shared__ float csL[512];                      // csx finalize (16b x 32c)

  if (threadIdx.x < 10) neN[threadIdx.x] = ne[n * 10 + threadIdx.x];
  __syncthreads();                                // BAR0: neN

  // ---- phase 1: rowS[m] = ne[n]·ne[m] (bit-identical fmaf order) ----
  #pragma unroll
  for (int g2 = 0; g2 < 2; ++g2) {
    const int m0 = g2 * 1024 + threadIdx.x * 4;
    float nm[40];
    const float4* nf = (const float4*)(ne + (size_t)m0 * 10);
    #pragma unroll
    for (int i = 0; i < 10; ++i) {
      float4 q = nf[i];
      nm[i * 4 + 0] = q.x; nm[i * 4 + 1] = q.y;
      nm[i * 4 + 2] = q.z; nm[i * 4 + 3] = q.w;
    }
    float res[4];
    #pragma unroll
    for (int rr = 0; rr < 4; ++rr) {
      float acc = 0.f;
      #pragma unroll
      for (int d = 0; d < 10; ++d)
        acc = fmaf(neN[d], nm[rr * 10 + d], acc);
      res[rr] = acc;
    }
    *(float4*)&rowS[m0] = make_float4(res[0], res[1], res[2], res[3]);
  }
  __syncthreads();                                // BAR1: rowS complete

  // ---- warp0: bound + compaction; warps 1-3: csL finalize (concurrent) ----
  if (warp == 0) {
    float lm = -3.4e38f;
    #pragma unroll
    for (int j = 0; j < 8; ++j) {
      float4 f = ((const float4*)rowS)[j * 64 + lane];
      lm = fmaxf(lm, fmaxf(fmaxf(f.x, f.y), fmaxf(f.z, f.w)));
    }
    float last = 3.4e38f;
    for (int rd = 0; rd < 11; ++rd) {
      float x2 = (lm < last) ? lm : -3.4e38f;
      #pragma unroll
      for (int off = 32; off > 0; off >>= 1) x2 = fmaxf(x2, __shfl_xor(x2, off));
      last = x2;
    }
    const float T = last - 0.0101f;               // a-space margin (s_b >= 1)

    int cnt = 0;
    #pragma unroll
    for (int slot = 0; slot < 32; ++slot) {
      float v = rowS[(slot >> 2) * 256 + lane * 4 + (slot & 3)];
      bool c = (v >= T);
      unsigned long long mk = __ballot(c);
      if (c) {
        int pos = cnt + __popcll(mk & ((1ull << lane) - 1ull));
        if (pos < 128) {
          candA[pos] = v;
          candM[pos] = ((slot >> 2) << 8) + (lane << 2) + (slot & 3);
        }
      }
      cnt += (int)__popcll(mk);
    }
    if (lane == 0) Cs = cnt < 128 ? cnt : 128;
  } else {
    // csx finalize: same ch order as r7 (bit-identical), entries 0..511
    for (int e = threadIdx.x - 64; e < 512; e += 192) {
      double s2 = 0.0;
      #pragma unroll
      for (int ch = 0; ch < 16; ++ch)
        s2 += partX[((((e >> 5) << 4) + ch) << 5) + (e & 31)];
      csL[e] = (float)s2;
    }
  }
  __syncthreads();                                // BAR2: candidates + csL

  const int C = Cs;
  const bool two = (C > 64);
  float a0c = 0.f, a1c = 0.f; int m0c = 0, m1c = 0;
  if (lane < C) { a0c = candA[lane]; m0c = candM[lane]; }
  if (two && lane + 64 < C) { a1c = candA[lane + 64]; m1c = candM[lane + 64]; }

  // ---- per-batch selection (barrier-free: per-warp slices, wave-ordered) ----
  for (int bi = 0; bi < 4; ++bi) {
    const int b = warp * 4 + bi;
    const int r = (b << 11) | n;

    float at = 0.f;
    #pragma unroll
    for (int d = 0; d < 8; ++d) at = fmaf(n_t[b * 8 + d], t[b * 8 + d], at);
    const float s = 1.0f + 0.3f * (1.0f / (1.0f + expf(-p[b])));

    float pre0 = fmaxf(s * (a0c + at), 0.f);
    unsigned long long k0 = 0ull;
    if (lane < C) {
      float key0 = pre0 + noise_val((unsigned)r * 2048u + (unsigned)m0c);
      k0 = ((unsigned long long)__float_as_uint(key0) << 32) |
           (unsigned)(2047 - m0c);
      keyS[warp][lane] = k0;
    }
    float pre1 = 0.f;
    unsigned long long k1 = 0ull;
    if (two) {
      if (lane + 64 < C) {
        pre1 = fmaxf(s * (a1c + at), 0.f);
        float key1 = pre1 + noise_val((unsigned)r * 2048u + (unsigned)m1c);
        k1 = ((unsigned long long)__float_as_uint(key1) << 32) |
             (unsigned)(2047 - m1c);
      }
      keyS[warp][lane + 64] = k1;
    }

    int rank0 = 0, rank1 = 0;
    for (int j2 = 0; j2 < C; ++j2) {
      unsigned long long kj = keyS[warp][j2];
      rank0 += (kj > k0) ? 1 : 0;
      if (two) rank1 += (kj > k1) ? 1 : 0;
    }
    bool w0 = (lane < C) && (rank0 < 10);
    bool w1 = two && (lane + 64 < C) && (rank1 < 10);

    float e0 = w0 ? expf(pre0) : 0.f;
    float e1 = w1 ? expf(pre1) : 0.f;
    float sum = e0 + e1;
    #pragma unroll
    for (int off = 32; off > 0; off >>= 1) sum += __shfl_xor(sum, off);
    const float ci = 1.0f / (2038.0f + sum);

    unsigned long long mk0 = __ballot(w0);
    if (w0) {
      int pos = __popcll(mk0 & ((1ull << lane) - 1ull));
      idxb[r * 10 + pos] = m0c;
      wgt[r * 10 + pos] = (e0 - 1.0f) * ci;
      winI[b][pos] = m0c;
      winW[b][pos] = (e0 - 1.0f) * ci;
    }
    if (two) {
      unsigned long long mk1 = __ballot(w1);
      int base = __popcll(mk0);
      if (w1) {
        int pos = base + __popcll(mk1 & ((1ull << lane) - 1ull));
        idxb[r * 10 + pos] = m1c;
        wgt[r * 10 + pos] = (e1 - 1.0f) * ci;
        winI[b][pos] = m1c;
        winW[b][pos] = (e1 - 1.0f) * ci;
      }
    }
    if (lane == 0) { cinv[r] = ci; ciS[b] = ci; }
  }

  // ---- Y1 phase (fused axpy): 2 passes x (2 rows x 32 cols) per warp ----
  #pragma unroll
  for (int pass = 0; pass < 2; ++pass) {
    const int bi2 = pass * 2 + (lane >> 5);
    const int b = warp * 4 + bi2;
    const int c = lane & 31;
    const int r = (b << 11) | n;
    float acc = ciS[b] * csL[(b << 5) + c];
    #pragma unroll
    for (int j = 0; j < 10; ++j) {
      int m = winI[b][j];
      float w = winW[b][j];
      acc = fmaf(w, x[(((b << 11) + m) << 5) + c], acc);
    }
    Y1[(size_t)r * 32 + c] = acc;
    atomicAdd(&csy_part[((n & 7) << 9) + (b << 5) + c], acc);
  }
}

// ---------------- K_v: Y2 = A@Y1 ; build V = [x, Y1, 2*Y2 - x] ----------------
__global__ __launch_bounds__(256) void k_v(const float* __restrict__ x,
                                           const float* __restrict__ Y1,
                                           const float* __restrict__ cinv,
                                           const int* __restrict__ idxb,
                                           const float* __restrict__ wgt,
                                           const float* __restrict__ csy_part,
                                           float* __restrict__ V) {
  int gid = blockIdx.x * 256 + threadIdx.x;
  int r = gid >> 5, c = gid & 31, b = r >> 11;
  float cs = 0.f;
  #pragma unroll
  for (int k = 0; k < 8; ++k) cs += csy_part[(k << 9) + (b << 5) + c];
  float y2 = cinv[r] * cs;
  #pragma unroll
  for (int j = 0; j < 10; ++j)
    y2 = fmaf(wgt[r * 10 + j], Y1[(((b << 11) + idxb[r * 10 + j]) << 5) + c], y2);
  float xv = x[gid], y1v = Y1[gid];
  V[r * 96 + c] = xv;
  V[r * 96 + 32 + c] = y1v;
  V[r * 96 + 64 + c] = 2.f * y2 - xv;
}

// ---------------- K_outn: node-term + bias, streaming Wn (1 node/block) ----------------
__global__ __launch_bounds__(256) void k_outn(const float* __restrict__ ne,
                                              const float* __restrict__ n_t,
                                              const float* __restrict__ Wn,
                                              const float* __restrict__ bp,
                                              const float* __restrict__ V,
                                              float* __restrict__ out) {
  const int n = blockIdx.x;                     // 2048 blocks
  __shared__ float Vs[16][100];
  __shared__ float bNs[64];

  for (int e = threadIdx.x; e < 384; e += 256) {
    int b = e / 24, j4 = e % 24;
    float4 f = *(const float4*)&V[((size_t)(b << 11) + n) * 96 + j4 * 4];
    *(float4*)&Vs[b][j4 * 4] = f;
  }
  if (threadIdx.x < 64) {
    float acc = 0.f;
    #pragma unroll
    for (int d = 0; d < 10; ++d)
      acc = fmaf(ne[n * 10 + d], bp[d * 64 + threadIdx.x], acc);
    bNs[threadIdx.x] = acc;
  }
  __syncthreads();

  const int b = threadIdx.x >> 4, og = threadIdx.x & 15;
  const float4* Wr = (const float4*)(Wn + (size_t)n * 6144);

  float4 acc = {0.f, 0.f, 0.f, 0.f};
  #pragma unroll 4
  for (int ki = 0; ki < 96; ++ki) {
    float4 wv = Wr[ki * 16 + og];
    float v = Vs[b][ki];
    acc.x = fmaf(v, wv.x, acc.x); acc.y = fmaf(v, wv.y, acc.y);
    acc.z = fmaf(v, wv.z, acc.z); acc.w = fmaf(v, wv.w, acc.w);
  }

  float4 res;
  #pragma unroll
  for (int q = 0; q < 4; ++q) {
    int o = og * 4 + q;
    float bT = 0.f;
    #pragma unroll
    for (int d = 0; d < 8; ++d)
      bT = fmaf(n_t[b * 8 + d], bp[(10 + d) * 64 + o], bT);
    (&res.x)[q] = (&acc.x)[q] + bNs[o] + bT;
  }
  *(float4*)&out[((size_t)(b << 11) + n) * 64 + og * 4] = res;
}

// ---------------- K_outt: out += V @ Wt[b] (Wt precomputed) ----------------
__global__ __launch_bounds__(512) void k_outt(const float* __restrict__ WtG,
                                              const float* __restrict__ V,
                                              float* __restrict__ out) {
  const int b = blockIdx.x >> 5, tile = blockIdx.x & 31;   // 512 blocks
  __shared__ float Wt[96][64];
  {
    const float4* src = (const float4*)(WtG + (size_t)b * 6144);
    float4* dst = (float4*)Wt;
    for (int e = threadIdx.x; e < 1536; e += 512) dst[e] = src[e];
  }
  __syncthreads();
  const int wave = threadIdx.x >> 6, lane = threadIdx.x & 63;
  const int og = lane & 15, rg = lane >> 4;
  const int r0 = tile * 64 + wave * 8 + rg * 2;

  float acc[2][4] = {};
  for (int ki4 = 0; ki4 < 24; ++ki4) {
    float4 vv[2];
    #pragma unroll
    for (int i = 0; i < 2; ++i)
      vv[i] = *(const float4*)&V[(size_t)((b << 11) + r0 + i) * 96 + ki4 * 4];
    #pragma unroll
    for (int t2 = 0; t2 < 4; ++t2) {
      float4 wv = *(const float4*)&Wt[ki4 * 4 + t2][og * 4];
      #pragma unroll
      for (int i = 0; i < 2; ++i) {
        float vi = (t2 == 0) ? vv[i].x : (t2 == 1) ? vv[i].y
                 : (t2 == 2) ? vv[i].z : vv[i].w;
        acc[i][0] = fmaf(vi, wv.x, acc[i][0]);
        acc[i][1] = fmaf(vi, wv.y, acc[i][1]);
        acc[i][2] = fmaf(vi, wv.z, acc[i][2]);
        acc[i][3] = fmaf(vi, wv.w, acc[i][3]);
      }
    }
  }
  #pragma unroll
  for (int i = 0; i < 2; ++i) {
    size_t oidx = (size_t)((b << 11) + r0 + i) * 64 + og * 4;
    float4 cur = *(float4*)&out[oidx];
    cur.x += acc[i][0]; cur.y += acc[i][1];
    cur.z += acc[i][2]; cur.w += acc[i][3];
    *(float4*)&out[oidx] = cur;
  }
}

extern "C" void kernel_launch(void* const* d_in, const int* in_sizes, int n_in,
                              void* d_out, int out_size, void* d_ws, size_t ws_size,
                              hipStream_t stream) {
  const float* x   = (const float*)d_in[0];
  const float* ne  = (const float*)d_in[1];
  const float* t   = (const float*)d_in[2];
  const float* n_t = (const float*)d_in[3];
  const float* p   = (const float*)d_in[4];
  const float* wp  = (const float*)d_in[5];
  const float* bp  = (const float*)d_in[6];
  float* out = (float*)d_out;
  float* ws = (float*)d_ws;
  (void)in_sizes; (void)n_in; (void)out_size; (void)ws_size;

  // layout (floats; ws is 268 MB)
  float* cinv     = ws;                         // 32,768
  int*   idxb     = (int*)(cinv + 32768);       // 327,680
  float* wgt      = (float*)(idxb + 327680);    // 327,680
  float* csy_part = wgt + 327680;               // 4,096 (8 partials x 512)
  double* partX   = (double*)(csy_part + 4096); // 8,192 doubles (8B-aligned)
  float* Y1       = (float*)(partX + 8192);     // 1,048,576
  float* V        = Y1 + 1048576;               // 3,145,728
  float* Wt       = V + 3145728;                // 98,304
  float* Wn       = Wt + 98304;                 // 12,582,912

  k_pre  <<<1121, 256, 0, stream>>>(ne, n_t, wp, x, Wn, Wt, partX, csy_part);
  k_topk <<<2048, 256, 0, stream>>>(ne, t, n_t, p, x, partX,
                                    cinv, idxb, wgt, Y1, csy_part);
  k_v    <<<4096, 256, 0, stream>>>(x, Y1, cinv, idxb, wgt, csy_part, V);
  k_outn <<<2048, 256, 0, stream>>>(ne, n_t, Wn, bp, V, out);
  k_outt <<<512, 512, 0, stream>>>(Wt, V, out);
}

// Round 10
// 179.648 us; speedup vs baseline: 1.2790x; 1.0133x over previous
//
#include <hip/hip_runtime.h>
#include <hip/hip_bf16.h>

// TGCN fused pipeline for MI355X (gfx950).
//  * A = softmax(pre*mask) = c_n*1^T + sparse(10/row)  ->  all graph convs are
//    O(N*TOPK*C) via colsum + 10-term gathers. No N^3 anywhere.
//  * Exact Threefry-2x32 replication of jax.random.uniform(key(42)) noise so
//    top-k tie-breaks match the reference bit-for-bit (verified r1-r9).
//  * pre = relu(s_b*(a+at_b)), s_b>=1  =>  pre-order == a-order; per-node
//    candidate hoisting + LDS rank-select (verified r4-r9).
// R10 (r9: k_topk 45.5us with VGPR_Count=36 -> nm[40] spilled to scratch
//      under __launch_bounds__(256,6); excess WRITE_SIZE confirms):
//  * phase 1 restructured to streaming accumulate (no 40-reg array);
//    e=4i+j -> (rr,d) compile-time mapping keeps fmaf order bit-identical.
//  * __launch_bounds__(256,4): 128-VGPR budget, no spill, same 16 waves/CU.

constexpr int BS = 16, NN_ = 2048, CIN = 32, OUT = 64, TK = 10;
constexpr int ROWS = BS * NN_;

// ---------------- Threefry-2x32 (matches jax._src.prng) ----------------
__device__ __forceinline__ void tf2x32(unsigned x0, unsigned x1,
                                       unsigned& o0, unsigned& o1) {
  const unsigned k0 = 0u, k1 = 42u;
  const unsigned ks2 = k0 ^ k1 ^ 0x1BD11BDAu;
#define TF_R(rot) { x0 += x1; x1 = (x1 << rot) | (x1 >> (32 - rot)); x1 ^= x0; }
  x0 += k0; x1 += k1;
  TF_R(13) TF_R(15) TF_R(26) TF_R(6)
  x0 += k1; x1 += ks2 + 1u;
  TF_R(17) TF_R(29) TF_R(16) TF_R(24)
  x0 += ks2; x1 += k0 + 2u;
  TF_R(13) TF_R(15) TF_R(26) TF_R(6)
  x0 += k0; x1 += k1 + 3u;
  TF_R(17) TF_R(29) TF_R(16) TF_R(24)
  x0 += k1; x1 += ks2 + 4u;
  TF_R(13) TF_R(15) TF_R(26) TF_R(6)
  x0 += ks2; x1 += k0 + 5u;
#undef TF_R
  o0 = x0; o1 = x1;
}

__device__ __forceinline__ float noise_val(unsigned flat) {
  unsigned o0, o1; tf2x32(0u, flat, o0, o1);
  unsigned bits = o0 ^ o1;
  float u = __uint_as_float((bits >> 9) | 0x3f800000u) - 1.0f;
  return 0.01f * u;
}

// ---------------- K_pre: Wn + Wt + partX (chunked) + csy_part zero ----------------
// [0,768): Wn[n][ki][o] = sum_d ne[n,d] wp[d,ki,o]
// [768,864): Wt[b][ki][o] = sum_d n_t[b,d] wp[10+d,ki,o]
// [864,1120): partX[b][ch][c] = partial colsum of x rows [ch*128,(ch+1)*128)
// 1120: zero csy_part[8][512]
__global__ __launch_bounds__(256) void k_pre(const float* __restrict__ ne,
                                             const float* __restrict__ n_t,
                                             const float* __restrict__ wp,
                                             const float* __restrict__ x,
                                             float* __restrict__ Wn,
                                             float* __restrict__ Wt,
                                             double* __restrict__ partX,
                                             float* __restrict__ csy_part) {
  const int bid = blockIdx.x;
  __shared__ float neS[16][10];
  __shared__ double red[8][32];

  if (bid < 768) {
    const int ng = bid / 6, sg = bid % 6;
    const int slot = sg * 256 + threadIdx.x;      // 1536 slots = 96 ki x 16 o4
    const int ki = slot >> 4, o4 = slot & 15;

    if (threadIdx.x < 160)
      neS[threadIdx.x / 10][threadIdx.x % 10] =
          ne[(ng * 16 + threadIdx.x / 10) * 10 + threadIdx.x % 10];

    const float4* wp4 = (const float4*)wp;
    float4 w[10];
    #pragma unroll
    for (int d = 0; d < 10; ++d) w[d] = wp4[(d * 96 + ki) * 16 + o4];
    __syncthreads();

    float4* Wn4 = (float4*)Wn;
    #pragma unroll 4
    for (int nn = 0; nn < 16; ++nn) {
      float4 acc = {0.f, 0.f, 0.f, 0.f};
      #pragma unroll
      for (int d = 0; d < 10; ++d) {
        float e = neS[nn][d];
        acc.x = fmaf(e, w[d].x, acc.x); acc.y = fmaf(e, w[d].y, acc.y);
        acc.z = fmaf(e, w[d].z, acc.z); acc.w = fmaf(e, w[d].w, acc.w);
      }
      Wn4[((size_t)(ng * 16 + nn) * 96 + ki) * 16 + o4] = acc;
    }
  } else if (bid < 864) {
    int gid = (bid - 768) * 256 + threadIdx.x;    // 24576 = 16*96*16
    int b = gid / 1536, rem = gid % 1536, ki = rem >> 4, o4 = rem & 15;
    const float4* wp4 = (const float4*)wp;
    float4 acc = {0.f, 0.f, 0.f, 0.f};
    #pragma unroll
    for (int d = 0; d < 8; ++d) {
      float e = n_t[b * 8 + d];
      float4 w = wp4[((10 + d) * 96 + ki) * 16 + o4];
      acc.x = fmaf(e, w.x, acc.x); acc.y = fmaf(e, w.y, acc.y);
      acc.z = fmaf(e, w.z, acc.z); acc.w = fmaf(e, w.w, acc.w);
    }
    ((float4*)Wt)[(b * 96 + ki) * 16 + o4] = acc;
  } else if (bid < 1120) {
    const int bb = bid - 864;
    const int b = bb >> 4, ch = bb & 15;
    const int c = threadIdx.x & 31, g = threadIdx.x >> 5;
    double acc = 0.0;
    for (int m = ch * 128 + g; m < ch * 128 + 128; m += 8)
      acc += (double)x[(((b << 11) + m) << 5) + c];
    red[g][c] = acc;
    __syncthreads();
    if (g == 0) {
      double s2 = red[0][c];
      #pragma unroll
      for (int i = 1; i < 8; ++i) s2 += red[i][c];
      partX[(((b << 4) + ch) << 5) + c] = s2;
    }
  } else {
    #pragma unroll
    for (int i = 0; i < 16; ++i) csy_part[i * 256 + threadIdx.x] = 0.f;
  }
}

// ---------------- K_topk: A0 row + top-k + Y1 + csy partials ----------------
// 2048 blocks x 256 thr; 1 node/block; warp w -> batches [w*4, w*4+4).
__global__ __launch_bounds__(256, 4) void k_topk(const float* __restrict__ ne,
                                                 const float* __restrict__ t,
                                                 const float* __restrict__ n_t,
                                                 const float* __restrict__ p,
                                                 const float* __restrict__ x,
                                                 const double* __restrict__ partX,
                                                 float* __restrict__ cinv,
                                                 int* __restrict__ idxb,
                                                 float* __restrict__ wgt,
                                                 float* __restrict__ Y1,
                                                 float* __restrict__ csy_part) {
  const int n = blockIdx.x;
  const int warp = threadIdx.x >> 6, lane = threadIdx.x & 63;

  __shared__ float rowS[2048];                    // 8 KiB
  __shared__ float neN[10];
  __shared__ float candA[128];
  __shared__ int   candM[128];
  __shared__ int   Cs;
  __shared__ unsigned long long keyS[4][128];     // 4 KiB, per-warp slices
  __shared__ int   winI[16][10];                  // per-batch winners
  __shared__ float winW[16][10];
  __shared__ float ciS[16];
  __shared__ float csL[512];                      // csx finalize (16b x 32c)

  if (threadIdx.x < 10) neN[threadIdx.x] = ne[n * 10 + threadIdx.x];
  __syncthreads();                                // BAR0: neN

  // ---- phase 1: rowS[m] = ne[n]·ne[m], streaming accumulate (no reg array).
  //      e=4i+j -> rr=e/10, d=e%10 ascending per rr => fmaf order identical
  //      to the original 10-FMA dot loop (bit-identical rowS).
  {
    float ner[10];
    #pragma unroll
    for (int d = 0; d < 10; ++d) ner[d] = neN[d];
    #pragma unroll
    for (int g2 = 0; g2 < 2; ++g2) {
      const int m0 = g2 * 1024 + threadIdx.x * 4;
      const float4* nf = (const float4*)(ne + (size_t)m0 * 10);
      float acc4[4] = {0.f, 0.f, 0.f, 0.f};
      #pragma unroll
      for (int i = 0; i < 10; ++i) {
        float4 q = nf[i];
        #pragma unroll
        for (int j = 0; j < 4; ++j) {
          const int e = i * 4 + j;
          const int rr = e / 10, d = e % 10;
          acc4[rr] = fmaf(ner[d], (&q.x)[j], acc4[rr]);
        }
      }
      *(float4*)&rowS[m0] = make_float4(acc4[0], acc4[1], acc4[2], acc4[3]);
    }
  }
  __syncthreads();                                // BAR1: rowS complete

  // ---- warp0: bound + compaction; warps 1-3: csL finalize (concurrent) ----
  if (warp == 0) {
    float lm = -3.4e38f;
    #pragma unroll
    for (int j = 0; j < 8; ++j) {
      float4 f = ((const float4*)rowS)[j * 64 + lane];
      lm = fmaxf(lm, fmaxf(fmaxf(f.x, f.y), fmaxf(f.z, f.w)));
    }
    float last = 3.4e38f;
    for (int rd = 0; rd < 11; ++rd) {
      float x2 = (lm < last) ? lm : -3.4e38f;
      #pragma unroll
      for (int off = 32; off > 0; off >>= 1) x2 = fmaxf(x2, __shfl_xor(x2, off));
      last = x2;
    }
    const float T = last - 0.0101f;               // a-space margin (s_b >= 1)

    int cnt = 0;
    #pragma unroll
    for (int slot = 0; slot < 32; ++slot) {
      float v = rowS[(slot >> 2) * 256 + lane * 4 + (slot & 3)];
      bool c = (v >= T);
      unsigned long long mk = __ballot(c);
      if (c) {
        int pos = cnt + __popcll(mk & ((1ull << lane) - 1ull));
        if (pos < 128) {
          candA[pos] = v;
          candM[pos] = ((slot >> 2) << 8) + (lane << 2) + (slot & 3);
        }
      }
      cnt += (int)__popcll(mk);
    }
    if (lane == 0) Cs = cnt < 128 ? cnt : 128;
  } else {
    // csx finalize: same ch order as r7 (bit-identical), entries 0..511
    for (int e = threadIdx.x - 64; e < 512; e += 192) {
      double s2 = 0.0;
      #pragma unroll
      for (int ch = 0; ch < 16; ++ch)
        s2 += partX[((((e >> 5) << 4) + ch) << 5) + (e & 31)];
      csL[e] = (float)s2;
    }
  }
  __syncthreads();                                // BAR2: candidates + csL

  const int C = Cs;
  const bool two = (C > 64);
  float a0c = 0.f, a1c = 0.f; int m0c = 0, m1c = 0;
  if (lane < C) { a0c = candA[lane]; m0c = candM[lane]; }
  if (two && lane + 64 < C) { a1c = candA[lane + 64]; m1c = candM[lane + 64]; }

  // ---- per-batch selection (barrier-free: per-warp slices, wave-ordered) ----
  for (int bi = 0; bi < 4; ++bi) {
    const int b = warp * 4 + bi;
    const int r = (b << 11) | n;

    float at = 0.f;
    #pragma unroll
    for (int d = 0; d < 8; ++d) at = fmaf(n_t[b * 8 + d], t[b * 8 + d], at);
    const float s = 1.0f + 0.3f * (1.0f / (1.0f + expf(-p[b])));

    float pre0 = fmaxf(s * (a0c + at), 0.f);
    unsigned long long k0 = 0ull;
    if (lane < C) {
      float key0 = pre0 + noise_val((unsigned)r * 2048u + (unsigned)m0c);
      k0 = ((unsigned long long)__float_as_uint(key0) << 32) |
           (unsigned)(2047 - m0c);
      keyS[warp][lane] = k0;
    }
    float pre1 = 0.f;
    unsigned long long k1 = 0ull;
    if (two) {
      if (lane + 64 < C) {
        pre1 = fmaxf(s * (a1c + at), 0.f);
        float key1 = pre1 + noise_val((unsigned)r * 2048u + (unsigned)m1c);
        k1 = ((unsigned long long)__float_as_uint(key1) << 32) |
             (unsigned)(2047 - m1c);
      }
      keyS[warp][lane + 64] = k1;
    }

    int rank0 = 0, rank1 = 0;
    for (int j2 = 0; j2 < C; ++j2) {
      unsigned long long kj = keyS[warp][j2];
      rank0 += (kj > k0) ? 1 : 0;
      if (two) rank1 += (kj > k1) ? 1 : 0;
    }
    bool w0 = (lane < C) && (rank0 < 10);
    bool w1 = two && (lane + 64 < C) && (rank1 < 10);

    float e0 = w0 ? expf(pre0) : 0.f;
    float e1 = w1 ? expf(pre1) : 0.f;
    float sum = e0 + e1;
    #pragma unroll
    for (int off = 32; off > 0; off >>= 1) sum += __shfl_xor(sum, off);
    const float ci = 1.0f / (2038.0f + sum);

    unsigned long long mk0 = __ballot(w0);
    if (w0) {
      int pos = __popcll(mk0 & ((1ull << lane) - 1ull));
      idxb[r * 10 + pos] = m0c;
      wgt[r * 10 + pos] = (e0 - 1.0f) * ci;
      winI[b][pos] = m0c;
      winW[b][pos] = (e0 - 1.0f) * ci;
    }
    if (two) {
      unsigned long long mk1 = __ballot(w1);
      int base = __popcll(mk0);
      if (w1) {
        int pos = base + __popcll(mk1 & ((1ull << lane) - 1ull));
        idxb[r * 10 + pos] = m1c;
        wgt[r * 10 + pos] = (e1 - 1.0f) * ci;
        winI[b][pos] = m1c;
        winW[b][pos] = (e1 - 1.0f) * ci;
      }
    }
    if (lane == 0) { cinv[r] = ci; ciS[b] = ci; }
  }

  // ---- Y1 phase (fused axpy): 2 passes x (2 rows x 32 cols) per warp ----
  #pragma unroll
  for (int pass = 0; pass < 2; ++pass) {
    const int bi2 = pass * 2 + (lane >> 5);
    const int b = warp * 4 + bi2;
    const int c = lane & 31;
    const int r = (b << 11) | n;
    float acc = ciS[b] * csL[(b << 5) + c];
    #pragma unroll
    for (int j = 0; j < 10; ++j) {
      int m = winI[b][j];
      float w = winW[b][j];
      acc = fmaf(w, x[(((b << 11) + m) << 5) + c], acc);
    }
    Y1[(size_t)r * 32 + c] = acc;
    atomicAdd(&csy_part[((n & 7) << 9) + (b << 5) + c], acc);
  }
}

// ---------------- K_v: Y2 = A@Y1 ; build V = [x, Y1, 2*Y2 - x] ----------------
__global__ __launch_bounds__(256) void k_v(const float* __restrict__ x,
                                           const float* __restrict__ Y1,
                                           const float* __restrict__ cinv,
                                           const int* __restrict__ idxb,
                                           const float* __restrict__ wgt,
                                           const float* __restrict__ csy_part,
                                           float* __restrict__ V) {
  int gid = blockIdx.x * 256 + threadIdx.x;
  int r = gid >> 5, c = gid & 31, b = r >> 11;
  float cs = 0.f;
  #pragma unroll
  for (int k = 0; k < 8; ++k) cs += csy_part[(k << 9) + (b << 5) + c];
  float y2 = cinv[r] * cs;
  #pragma unroll
  for (int j = 0; j < 10; ++j)
    y2 = fmaf(wgt[r * 10 + j], Y1[(((b << 11) + idxb[r * 10 + j]) << 5) + c], y2);
  float xv = x[gid], y1v = Y1[gid];
  V[r * 96 + c] = xv;
  V[r * 96 + 32 + c] = y1v;
  V[r * 96 + 64 + c] = 2.f * y2 - xv;
}

// ---------------- K_outn: node-term + bias, streaming Wn (1 node/block) ----------------
__global__ __launch_bounds__(256) void k_outn(const float* __restrict__ ne,
                                              const float* __restrict__ n_t,
                                              const float* __restrict__ Wn,
                                              const float* __restrict__ bp,
                                              const float* __restrict__ V,
                                              float* __restrict__ out) {
  const int n = blockIdx.x;                     // 2048 blocks
  __shared__ float Vs[16][100];
  __shared__ float bNs[64];

  for (int e = threadIdx.x; e < 384; e += 256) {
    int b = e / 24, j4 = e % 24;
    float4 f = *(const float4*)&V[((size_t)(b << 11) + n) * 96 + j4 * 4];
    *(float4*)&Vs[b][j4 * 4] = f;
  }
  if (threadIdx.x < 64) {
    float acc = 0.f;
    #pragma unroll
    for (int d = 0; d < 10; ++d)
      acc = fmaf(ne[n * 10 + d], bp[d * 64 + threadIdx.x], acc);
    bNs[threadIdx.x] = acc;
  }
  __syncthreads();

  const int b = threadIdx.x >> 4, og = threadIdx.x & 15;
  const float4* Wr = (const float4*)(Wn + (size_t)n * 6144);

  float4 acc = {0.f, 0.f, 0.f, 0.f};
  #pragma unroll 4
  for (int ki = 0; ki < 96; ++ki) {
    float4 wv = Wr[ki * 16 + og];
    float v = Vs[b][ki];
    acc.x = fmaf(v, wv.x, acc.x); acc.y = fmaf(v, wv.y, acc.y);
    acc.z = fmaf(v, wv.z, acc.z); acc.w = fmaf(v, wv.w, acc.w);
  }

  float4 res;
  #pragma unroll
  for (int q = 0; q < 4; ++q) {
    int o = og * 4 + q;
    float bT = 0.f;
    #pragma unroll
    for (int d = 0; d < 8; ++d)
      bT = fmaf(n_t[b * 8 + d], bp[(10 + d) * 64 + o], bT);
    (&res.x)[q] = (&acc.x)[q] + bNs[o] + bT;
  }
  *(float4*)&out[((size_t)(b << 11) + n) * 64 + og * 4] = res;
}

// ---------------- K_outt: out += V @ Wt[b] (Wt precomputed) ----------------
__global__ __launch_bounds__(512) void k_outt(const float* __restrict__ WtG,
                                              const float* __restrict__ V,
                                              float* __restrict__ out) {
  const int b = blockIdx.x >> 5, tile = blockIdx.x & 31;   // 512 blocks
  __shared__ float Wt[96][64];
  {
    const float4* src = (const float4*)(WtG + (size_t)b * 6144);
    float4* dst = (float4*)Wt;
    for (int e = threadIdx.x; e < 1536; e += 512) dst[e] = src[e];
  }
  __syncthreads();
  const int wave = threadIdx.x >> 6, lane = threadIdx.x & 63;
  const int og = lane & 15, rg = lane >> 4;
  const int r0 = tile * 64 + wave * 8 + rg * 2;

  float acc[2][4] = {};
  for (int ki4 = 0; ki4 < 24; ++ki4) {
    float4 vv[2];
    #pragma unroll
    for (int i = 0; i < 2; ++i)
      vv[i] = *(const float4*)&V[(size_t)((b << 11) + r0 + i) * 96 + ki4 * 4];
    #pragma unroll
    for (int t2 = 0; t2 < 4; ++t2) {
      float4 wv = *(const float4*)&Wt[ki4 * 4 + t2][og * 4];
      #pragma unroll
      for (int i = 0; i < 2; ++i) {
        float vi = (t2 == 0) ? vv[i].x : (t2 == 1) ? vv[i].y
                 : (t2 == 2) ? vv[i].z : vv[i].w;
        acc[i][0] = fmaf(vi, wv.x, acc[i][0]);
        acc[i][1] = fmaf(vi, wv.y, acc[i][1]);
        acc[i][2] = fmaf(vi, wv.z, acc[i][2]);
        acc[i][3] = fmaf(vi, wv.w, acc[i][3]);
      }
    }
  }
  #pragma unroll
  for (int i = 0; i < 2; ++i) {
    size_t oidx = (size_t)((b << 11) + r0 + i) * 64 + og * 4;
    float4 cur = *(float4*)&out[oidx];
    cur.x += acc[i][0]; cur.y += acc[i][1];
    cur.z += acc[i][2]; cur.w += acc[i][3];
    *(float4*)&out[oidx] = cur;
  }
}

extern "C" void kernel_launch(void* const* d_in, const int* in_sizes, int n_in,
                              void* d_out, int out_size, void* d_ws, size_t ws_size,
                              hipStream_t stream) {
  const float* x   = (const float*)d_in[0];
  const float* ne  = (const float*)d_in[1];
  const float* t   = (const float*)d_in[2];
  const float* n_t = (const float*)d_in[3];
  const float* p   = (const float*)d_in[4];
  const float* wp  = (const float*)d_in[5];
  const float* bp  = (const float*)d_in[6];
  float* out = (float*)d_out;
  float* ws = (float*)d_ws;
  (void)in_sizes; (void)n_in; (void)out_size; (void)ws_size;

  // layout (floats; ws is 268 MB)
  float* cinv     = ws;                         // 32,768
  int*   idxb     = (int*)(cinv + 32768);       // 327,680
  float* wgt      = (float*)(idxb + 327680);    // 327,680
  float* csy_part = wgt + 327680;               // 4,096 (8 partials x 512)
  double* partX   = (double*)(csy_part + 4096); // 8,192 doubles (8B-aligned)
  float* Y1       = (float*)(partX + 8192);     // 1,048,576
  float* V        = Y1 + 1048576;               // 3,145,728
  float* Wt       = V + 3145728;                // 98,304
  float* Wn       = Wt + 98304;                 // 12,582,912

  k_pre  <<<1121, 256, 0, stream>>>(ne, n_t, wp, x, Wn, Wt, partX, csy_part);
  k_topk <<<2048, 256, 0, stream>>>(ne, t, n_t, p, x, partX,
                                    cinv, idxb, wgt, Y1, csy_part);
  k_v    <<<4096, 256, 0, stream>>>(x, Y1, cinv, idxb, wgt, csy_part, V);
  k_outn <<<2048, 256, 0, stream>>>(ne, n_t, Wn, bp, V, out);
  k_outt <<<512, 512, 0, stream>>>(Wt, V, out);
}

// Round 11
// 173.810 us; speedup vs baseline: 1.3220x; 1.0336x over previous
//
#include <hip/hip_runtime.h>
#include <hip/hip_bf16.h>

// TGCN fused pipeline for MI355X (gfx950).
//  * A = softmax(pre*mask) = c_n*1^T + sparse(10/row)  ->  all graph convs are
//    O(N*TOPK*C) via colsum + 10-term gathers. No N^3 anywhere.
//  * Exact Threefry-2x32 replication of jax.random.uniform(key(42)) noise so
//    top-k tie-breaks match the reference bit-for-bit (verified r1-r10).
//  * pre = relu(s_b*(a+at_b)), s_b>=1  =>  pre-order == a-order; per-node
//    candidate hoisting + LDS rank-select (verified r4-r10).
// R11 (r10 neutral: no spill after all; VALUBusy 36% = lane utilization —
//      selection runs with only C~20 of 64 lanes active):
//  * k_topk fast path (C<=32): half-wave batch pairing — lanes 0-31 serve one
//    batch, 32-63 another; dense threefry, per-half rank/reduce/ballot.
//    4 sparse passes/warp -> 2 dense. C>32 keeps r10 path verbatim.
//  * csx via atomicAdd(double) in k_pre (csxD zeroed by one hipMemsetAsync);
//    partX + per-block csL finalize removed (-131 MB L2).
//  * Per-warp compaction (no warp0 serialization); k_topk: 1 barrier total.

constexpr int BS = 16, NN_ = 2048, CIN = 32, OUT = 64, TK = 10;
constexpr int ROWS = BS * NN_;

// ---------------- Threefry-2x32 (matches jax._src.prng) ----------------
__device__ __forceinline__ void tf2x32(unsigned x0, unsigned x1,
                                       unsigned& o0, unsigned& o1) {
  const unsigned k0 = 0u, k1 = 42u;
  const unsigned ks2 = k0 ^ k1 ^ 0x1BD11BDAu;
#define TF_R(rot) { x0 += x1; x1 = (x1 << rot) | (x1 >> (32 - rot)); x1 ^= x0; }
  x0 += k0; x1 += k1;
  TF_R(13) TF_R(15) TF_R(26) TF_R(6)
  x0 += k1; x1 += ks2 + 1u;
  TF_R(17) TF_R(29) TF_R(16) TF_R(24)
  x0 += ks2; x1 += k0 + 2u;
  TF_R(13) TF_R(15) TF_R(26) TF_R(6)
  x0 += k0; x1 += k1 + 3u;
  TF_R(17) TF_R(29) TF_R(16) TF_R(24)
  x0 += k1; x1 += ks2 + 4u;
  TF_R(13) TF_R(15) TF_R(26) TF_R(6)
  x0 += ks2; x1 += k0 + 5u;
#undef TF_R
  o0 = x0; o1 = x1;
}

__device__ __forceinline__ float noise_val(unsigned flat) {
  unsigned o0, o1; tf2x32(0u, flat, o0, o1);
  unsigned bits = o0 ^ o1;
  float u = __uint_as_float((bits >> 9) | 0x3f800000u) - 1.0f;
  return 0.01f * u;
}

// ---------------- K_pre: Wn + Wt + csx double-atomics ----------------
// [0,768): Wn[n][ki][o] = sum_d ne[n,d] wp[d,ki,o]
// [768,864): Wt[b][ki][o] = sum_d n_t[b,d] wp[10+d,ki,o]
// [864,1120): chunk colsum of x -> atomicAdd(double) into csxD[b*32+c]
__global__ __launch_bounds__(256) void k_pre(const float* __restrict__ ne,
                                             const float* __restrict__ n_t,
                                             const float* __restrict__ wp,
                                             const float* __restrict__ x,
                                             float* __restrict__ Wn,
                                             float* __restrict__ Wt,
                                             double* __restrict__ csxD) {
  const int bid = blockIdx.x;
  __shared__ float neS[16][10];
  __shared__ double red[8][32];

  if (bid < 768) {
    const int ng = bid / 6, sg = bid % 6;
    const int slot = sg * 256 + threadIdx.x;      // 1536 slots = 96 ki x 16 o4
    const int ki = slot >> 4, o4 = slot & 15;

    if (threadIdx.x < 160)
      neS[threadIdx.x / 10][threadIdx.x % 10] =
          ne[(ng * 16 + threadIdx.x / 10) * 10 + threadIdx.x % 10];

    const float4* wp4 = (const float4*)wp;
    float4 w[10];
    #pragma unroll
    for (int d = 0; d < 10; ++d) w[d] = wp4[(d * 96 + ki) * 16 + o4];
    __syncthreads();

    float4* Wn4 = (float4*)Wn;
    #pragma unroll 4
    for (int nn = 0; nn < 16; ++nn) {
      float4 acc = {0.f, 0.f, 0.f, 0.f};
      #pragma unroll
      for (int d = 0; d < 10; ++d) {
        float e = neS[nn][d];
        acc.x = fmaf(e, w[d].x, acc.x); acc.y = fmaf(e, w[d].y, acc.y);
        acc.z = fmaf(e, w[d].z, acc.z); acc.w = fmaf(e, w[d].w, acc.w);
      }
      Wn4[((size_t)(ng * 16 + nn) * 96 + ki) * 16 + o4] = acc;
    }
  } else if (bid < 864) {
    int gid = (bid - 768) * 256 + threadIdx.x;    // 24576 = 16*96*16
    int b = gid / 1536, rem = gid % 1536, ki = rem >> 4, o4 = rem & 15;
    const float4* wp4 = (const float4*)wp;
    float4 acc = {0.f, 0.f, 0.f, 0.f};
    #pragma unroll
    for (int d = 0; d < 8; ++d) {
      float e = n_t[b * 8 + d];
      float4 w = wp4[((10 + d) * 96 + ki) * 16 + o4];
      acc.x = fmaf(e, w.x, acc.x); acc.y = fmaf(e, w.y, acc.y);
      acc.z = fmaf(e, w.z, acc.z); acc.w = fmaf(e, w.w, acc.w);
    }
    ((float4*)Wt)[(b * 96 + ki) * 16 + o4] = acc;
  } else {
    const int bb = bid - 864;
    const int b = bb >> 4, ch = bb & 15;
    const int c = threadIdx.x & 31, g = threadIdx.x >> 5;
    double acc = 0.0;
    for (int m = ch * 128 + g; m < ch * 128 + 128; m += 8)
      acc += (double)x[(((b << 11) + m) << 5) + c];
    red[g][c] = acc;
    __syncthreads();
    if (g == 0) {
      double s2 = red[0][c];
      #pragma unroll
      for (int i = 1; i < 8; ++i) s2 += red[i][c];
      atomicAdd(&csxD[(b << 5) + c], s2);
    }
  }
}

// ---------------- K_topk: A0 row + top-k + Y1 + csy partials ----------------
// 2048 blocks x 256 thr; 1 node/block; warp w -> batches [w*4, w*4+4).
__global__ __launch_bounds__(256, 4) void k_topk(const float* __restrict__ ne,
                                                 const float* __restrict__ t,
                                                 const float* __restrict__ n_t,
                                                 const float* __restrict__ p,
                                                 const float* __restrict__ x,
                                                 const double* __restrict__ csxD,
                                                 float* __restrict__ cinv,
                                                 int* __restrict__ idxb,
                                                 float* __restrict__ wgt,
                                                 float* __restrict__ Y1,
                                                 float* __restrict__ csy_part) {
  const int n = blockIdx.x;
  const int warp = threadIdx.x >> 6, lane = threadIdx.x & 63;

  __shared__ float rowS[2048];                    // 8 KiB
  __shared__ float candA[4][128];                 // per-warp slices
  __shared__ int   candM[4][128];
  __shared__ unsigned long long keyS[4][128];     // per-warp slices
  __shared__ int   winI[16][10];                  // per-batch winners
  __shared__ float winW[16][10];
  __shared__ float ciS[16];

  // ---- phase 1: rowS[m] = ne[n]·ne[m] (block-uniform ne[n] -> s_loads).
  //      Streaming accumulate; fmaf order identical to original dot loop.
  {
    float ner[10];
    #pragma unroll
    for (int d = 0; d < 10; ++d) ner[d] = ne[n * 10 + d];
    #pragma unroll
    for (int g2 = 0; g2 < 2; ++g2) {
      const int m0 = g2 * 1024 + threadIdx.x * 4;
      const float4* nf = (const float4*)(ne + (size_t)m0 * 10);
      float acc4[4] = {0.f, 0.f, 0.f, 0.f};
      #pragma unroll
      for (int i = 0; i < 10; ++i) {
        float4 q = nf[i];
        #pragma unroll
        for (int j = 0; j < 4; ++j) {
          const int e = i * 4 + j;
          const int rr = e / 10, d = e % 10;
          acc4[rr] = fmaf(ner[d], (&q.x)[j], acc4[rr]);
        }
      }
      *(float4*)&rowS[m0] = make_float4(acc4[0], acc4[1], acc4[2], acc4[3]);
    }
  }
  __syncthreads();                                // BAR1: rowS complete (only barrier)

  // ---- per-warp: 11th-distinct-lane-max bound + candidate compaction ----
  float lm = -3.4e38f;
  #pragma unroll
  for (int j = 0; j < 8; ++j) {
    float4 f = ((const float4*)rowS)[j * 64 + lane];
    lm = fmaxf(lm, fmaxf(fmaxf(f.x, f.y), fmaxf(f.z, f.w)));
  }
  float last = 3.4e38f;
  for (int rd = 0; rd < 11; ++rd) {
    float x2 = (lm < last) ? lm : -3.4e38f;
    #pragma unroll
    for (int off = 32; off > 0; off >>= 1) x2 = fmaxf(x2, __shfl_xor(x2, off));
    last = x2;
  }
  const float T = last - 0.0101f;                 // a-space margin (s_b >= 1)

  int cnt = 0;
  #pragma unroll
  for (int slot = 0; slot < 32; ++slot) {
    float v = rowS[(slot >> 2) * 256 + lane * 4 + (slot & 3)];
    bool c = (v >= T);
    unsigned long long mk = __ballot(c);
    if (c) {
      int pos = cnt + __popcll(mk & ((1ull << lane) - 1ull));
      if (pos < 128) {
        candA[warp][pos] = v;
        candM[warp][pos] = ((slot >> 2) << 8) + (lane << 2) + (slot & 3);
      }
    }
    cnt += (int)__popcll(mk);
  }
  const int C = cnt < 128 ? cnt : 128;

  if (C <= 32) {
    // ======== FAST PATH: half-wave batch pairing (dense lanes) ========
    const int h = lane >> 5, j = lane & 31;
    for (int pair = 0; pair < 2; ++pair) {
      const int b = warp * 4 + pair * 2 + h;
      const int r = (b << 11) | n;

      float at = 0.f;
      #pragma unroll
      for (int d = 0; d < 8; ++d) at = fmaf(n_t[b * 8 + d], t[b * 8 + d], at);
      const float s = 1.0f + 0.3f * (1.0f / (1.0f + expf(-p[b])));

      const bool act = (j < C);
      float pre = 0.f; int mj = 0;
      unsigned long long kk = 0ull;
      if (act) {
        float aj = candA[warp][j]; mj = candM[warp][j];
        pre = fmaxf(s * (aj + at), 0.f);
        float key = pre + noise_val((unsigned)r * 2048u + (unsigned)mj);
        kk = ((unsigned long long)__float_as_uint(key) << 32) |
             (unsigned)(2047 - mj);
      }
      keyS[warp][lane] = kk;

      int rank = 0;
      for (int j2 = 0; j2 < C; ++j2) {
        unsigned long long kj = keyS[warp][h * 32 + j2];
        rank += (kj > kk) ? 1 : 0;
      }
      const bool win = act && (rank < 10);

      float e = win ? expf(pre) : 0.f;
      float sum = e;
      #pragma unroll
      for (int off = 16; off > 0; off >>= 1) sum += __shfl_xor(sum, off);
      const float ci = 1.0f / (2038.0f + sum);

      unsigned long long mask = __ballot(win);
      unsigned mh = (unsigned)(mask >> (h * 32));
      if (win) {
        int pos = __popc(mh & ((1u << j) - 1u));
        idxb[r * 10 + pos] = mj;
        wgt[r * 10 + pos] = (e - 1.0f) * ci;
        winI[b][pos] = mj;
        winW[b][pos] = (e - 1.0f) * ci;
      }
      if (j == 0) { cinv[r] = ci; ciS[b] = ci; }
    }
  } else {
    // ======== FALLBACK (C in (32,128]): r10-verified full-wave path ========
    const bool two = (C > 64);
    float a0c = 0.f, a1c = 0.f; int m0c = 0, m1c = 0;
    if (lane < C) { a0c = candA[warp][lane]; m0c = candM[warp][lane]; }
    if (two && lane + 64 < C) {
      a1c = candA[warp][lane + 64]; m1c = candM[warp][lane + 64];
    }
    for (int bi = 0; bi < 4; ++bi) {
      const int b = warp * 4 + bi;
      const int r = (b << 11) | n;

      float at = 0.f;
      #pragma unroll
      for (int d = 0; d < 8; ++d) at = fmaf(n_t[b * 8 + d], t[b * 8 + d], at);
      const float s = 1.0f + 0.3f * (1.0f / (1.0f + expf(-p[b])));

      float pre0 = fmaxf(s * (a0c + at), 0.f);
      unsigned long long k0 = 0ull;
      if (lane < C) {
        float key0 = pre0 + noise_val((unsigned)r * 2048u + (unsigned)m0c);
        k0 = ((unsigned long long)__float_as_uint(key0) << 32) |
             (unsigned)(2047 - m0c);
        keyS[warp][lane] = k0;
      }
      float pre1 = 0.f;
      unsigned long long k1 = 0ull;
      if (two) {
        if (lane + 64 < C) {
          pre1 = fmaxf(s * (a1c + at), 0.f);
          float key1 = pre1 + noise_val((unsigned)r * 2048u + (unsigned)m1c);
          k1 = ((unsigned long long)__float_as_uint(key1) << 32) |
               (unsigned)(2047 - m1c);
        }
        keyS[warp][lane + 64] = k1;
      }

      int rank0 = 0, rank1 = 0;
      for (int j2 = 0; j2 < C; ++j2) {
        unsigned long long kj = keyS[warp][j2];
        rank0 += (kj > k0) ? 1 : 0;
        if (two) rank1 += (kj > k1) ? 1 : 0;
      }
      bool w0 = (lane < C) && (rank0 < 10);
      bool w1 = two && (lane + 64 < C) && (rank1 < 10);

      float e0 = w0 ? expf(pre0) : 0.f;
      float e1 = w1 ? expf(pre1) : 0.f;
      float sum = e0 + e1;
      #pragma unroll
      for (int off = 32; off > 0; off >>= 1) sum += __shfl_xor(sum, off);
      const float ci = 1.0f / (2038.0f + sum);

      unsigned long long mk0 = __ballot(w0);
      if (w0) {
        int pos = __popcll(mk0 & ((1ull << lane) - 1ull));
        idxb[r * 10 + pos] = m0c;
        wgt[r * 10 + pos] = (e0 - 1.0f) * ci;
        winI[b][pos] = m0c;
        winW[b][pos] = (e0 - 1.0f) * ci;
      }
      if (two) {
        unsigned long long mk1 = __ballot(w1);
        int base = __popcll(mk0);
        if (w1) {
          int pos = base + __popcll(mk1 & ((1ull << lane) - 1ull));
          idxb[r * 10 + pos] = m1c;
          wgt[r * 10 + pos] = (e1 - 1.0f) * ci;
          winI[b][pos] = m1c;
          winW[b][pos] = (e1 - 1.0f) * ci;
        }
      }
      if (lane == 0) { cinv[r] = ci; ciS[b] = ci; }
    }
  }

  // ---- Y1 phase (fused axpy): 2 passes x (2 rows x 32 cols) per warp ----
  #pragma unroll
  for (int pass = 0; pass < 2; ++pass) {
    const int bi2 = pass * 2 + (lane >> 5);
    const int b = warp * 4 + bi2;
    const int c = lane & 31;
    const int r = (b << 11) | n;
    float acc = ciS[b] * (float)csxD[(b << 5) + c];
    #pragma unroll
    for (int j = 0; j < 10; ++j) {
      int m = winI[b][j];
      float w = winW[b][j];
      acc = fmaf(w, x[(((b << 11) + m) << 5) + c], acc);
    }
    Y1[(size_t)r * 32 + c] = acc;
    atomicAdd(&csy_part[((n & 7) << 9) + (b << 5) + c], acc);
  }
}

// ---------------- K_v: Y2 = A@Y1 ; build V = [x, Y1, 2*Y2 - x] ----------------
__global__ __launch_bounds__(256) void k_v(const float* __restrict__ x,
                                           const float* __restrict__ Y1,
                                           const float* __restrict__ cinv,
                                           const int* __restrict__ idxb,
                                           const float* __restrict__ wgt,
                                           const float* __restrict__ csy_part,
                                           float* __restrict__ V) {
  int gid = blockIdx.x * 256 + threadIdx.x;
  int r = gid >> 5, c = gid & 31, b = r >> 11;
  float cs = 0.f;
  #pragma unroll
  for (int k = 0; k < 8; ++k) cs += csy_part[(k << 9) + (b << 5) + c];
  float y2 = cinv[r] * cs;
  #pragma unroll
  for (int j = 0; j < 10; ++j)
    y2 = fmaf(wgt[r * 10 + j], Y1[(((b << 11) + idxb[r * 10 + j]) << 5) + c], y2);
  float xv = x[gid], y1v = Y1[gid];
  V[r * 96 + c] = xv;
  V[r * 96 + 32 + c] = y1v;
  V[r * 96 + 64 + c] = 2.f * y2 - xv;
}

// ---------------- K_outn: node-term + bias, streaming Wn (1 node/block) ----------------
__global__ __launch_bounds__(256) void k_outn(const float* __restrict__ ne,
                                              const float* __restrict__ n_t,
                                              const float* __restrict__ Wn,
                                              const float* __restrict__ bp,
                                              const float* __restrict__ V,
                                              float* __restrict__ out) {
  const int n = blockIdx.x;                     // 2048 blocks
  __shared__ float Vs[16][100];
  __shared__ float bNs[64];

  for (int e = threadIdx.x; e < 384; e += 256) {
    int b = e / 24, j4 = e % 24;
    float4 f = *(const float4*)&V[((size_t)(b << 11) + n) * 96 + j4 * 4];
    *(float4*)&Vs[b][j4 * 4] = f;
  }
  if (threadIdx.x < 64) {
    float acc = 0.f;
    #pragma unroll
    for (int d = 0; d < 10; ++d)
      acc = fmaf(ne[n * 10 + d], bp[d * 64 + threadIdx.x], acc);
    bNs[threadIdx.x] = acc;
  }
  __syncthreads();

  const int b = threadIdx.x >> 4, og = threadIdx.x & 15;
  const float4* Wr = (const float4*)(Wn + (size_t)n * 6144);

  float4 acc = {0.f, 0.f, 0.f, 0.f};
  #pragma unroll 4
  for (int ki = 0; ki < 96; ++ki) {
    float4 wv = Wr[ki * 16 + og];
    float v = Vs[b][ki];
    acc.x = fmaf(v, wv.x, acc.x); acc.y = fmaf(v, wv.y, acc.y);
    acc.z = fmaf(v, wv.z, acc.z); acc.w = fmaf(v, wv.w, acc.w);
  }

  float4 res;
  #pragma unroll
  for (int q = 0; q < 4; ++q) {
    int o = og * 4 + q;
    float bT = 0.f;
    #pragma unroll
    for (int d = 0; d < 8; ++d)
      bT = fmaf(n_t[b * 8 + d], bp[(10 + d) * 64 + o], bT);
    (&res.x)[q] = (&acc.x)[q] + bNs[o] + bT;
  }
  *(float4*)&out[((size_t)(b << 11) + n) * 64 + og * 4] = res;
}

// ---------------- K_outt: out += V @ Wt[b] (Wt precomputed) ----------------
__global__ __launch_bounds__(512) void k_outt(const float* __restrict__ WtG,
                                              const float* __restrict__ V,
                                              float* __restrict__ out) {
  const int b = blockIdx.x >> 5, tile = blockIdx.x & 31;   // 512 blocks
  __shared__ float Wt[96][64];
  {
    const float4* src = (const float4*)(WtG + (size_t)b * 6144);
    float4* dst = (float4*)Wt;
    for (int e = threadIdx.x; e < 1536; e += 512) dst[e] = src[e];
  }
  __syncthreads();
  const int wave = threadIdx.x >> 6, lane = threadIdx.x & 63;
  const int og = lane & 15, rg = lane >> 4;
  const int r0 = tile * 64 + wave * 8 + rg * 2;

  float acc[2][4] = {};
  for (int ki4 = 0; ki4 < 24; ++ki4) {
    float4 vv[2];
    #pragma unroll
    for (int i = 0; i < 2; ++i)
      vv[i] = *(const float4*)&V[(size_t)((b << 11) + r0 + i) * 96 + ki4 * 4];
    #pragma unroll
    for (int t2 = 0; t2 < 4; ++t2) {
      float4 wv = *(const float4*)&Wt[ki4 * 4 + t2][og * 4];
      #pragma unroll
      for (int i = 0; i < 2; ++i) {
        float vi = (t2 == 0) ? vv[i].x : (t2 == 1) ? vv[i].y
                 : (t2 == 2) ? vv[i].z : vv[i].w;
        acc[i][0] = fmaf(vi, wv.x, acc[i][0]);
        acc[i][1] = fmaf(vi, wv.y, acc[i][1]);
        acc[i][2] = fmaf(vi, wv.z, acc[i][2]);
        acc[i][3] = fmaf(vi, wv.w, acc[i][3]);
      }
    }
  }
  #pragma unroll
  for (int i = 0; i < 2; ++i) {
    size_t oidx = (size_t)((b << 11) + r0 + i) * 64 + og * 4;
    float4 cur = *(float4*)&out[oidx];
    cur.x += acc[i][0]; cur.y += acc[i][1];
    cur.z += acc[i][2]; cur.w += acc[i][3];
    *(float4*)&out[oidx] = cur;
  }
}

extern "C" void kernel_launch(void* const* d_in, const int* in_sizes, int n_in,
                              void* d_out, int out_size, void* d_ws, size_t ws_size,
                              hipStream_t stream) {
  const float* x   = (const float*)d_in[0];
  const float* ne  = (const float*)d_in[1];
  const float* t   = (const float*)d_in[2];
  const float* n_t = (const float*)d_in[3];
  const float* p   = (const float*)d_in[4];
  const float* wp  = (const float*)d_in[5];
  const float* bp  = (const float*)d_in[6];
  float* out = (float*)d_out;
  float* ws = (float*)d_ws;
  (void)in_sizes; (void)n_in; (void)out_size; (void)ws_size;

  // layout (floats; ws is 268 MB). csxD offset = 2,752,512 B (8B-aligned).
  float* cinv     = ws;                         // 32,768
  int*   idxb     = (int*)(cinv + 32768);       // 327,680
  float* wgt      = (float*)(idxb + 327680);    // 327,680
  double* csxD    = (double*)(wgt + 327680);    // 512 doubles
  float* csy_part = (float*)(csxD + 512);       // 4,096 (8 partials x 512)
  float* Y1       = csy_part + 4096;            // 1,048,576
  float* V        = Y1 + 1048576;               // 3,145,728
  float* Wt       = V + 3145728;                // 98,304
  float* Wn       = Wt + 98304;                 // 12,582,912

  // zero csxD (4 KB) + csy_part (16 KB) in one capture-safe memset node
  hipMemsetAsync(csxD, 0, 512 * 8 + 4096 * 4, stream);

  k_pre  <<<1120, 256, 0, stream>>>(ne, n_t, wp, x, Wn, Wt, csxD);
  k_topk <<<2048, 256, 0, stream>>>(ne, t, n_t, p, x, csxD,
                                    cinv, idxb, wgt, Y1, csy_part);
  k_v    <<<4096, 256, 0, stream>>>(x, Y1, cinv, idxb, wgt, csy_part, V);
  k_outn <<<2048, 256, 0, stream>>>(ne, n_t, Wn, bp, V, out);
  k_outt <<<512, 512, 0, stream>>>(Wt, V, out);
}

// Round 12
// 171.249 us; speedup vs baseline: 1.3418x; 1.0150x over previous
//
#include <hip/hip_runtime.h>
#include <hip/hip_bf16.h>

// TGCN fused pipeline for MI355X (gfx950).
//  * A = softmax(pre*mask) = c_n*1^T + sparse(10/row)  ->  all graph convs are
//    O(N*TOPK*C) via colsum + 10-term gathers. No N^3 anywhere.
//  * Exact Threefry-2x32 replication of jax.random.uniform(key(42)) noise so
//    top-k tie-breaks match the reference bit-for-bit (verified r1-r11).
//  * pre = relu(s_b*(a+at_b)), s_b>=1  =>  pre-order == a-order; per-node
//    candidate hoisting + LDS rank-select + half-wave pairing (r4-r11).
// R12 (r11: top-5 all harness-fill; false serialization is the lever):
//  * Wn/Wt compute folded into k_topk as extra blocks (bid<864) — memory-
//    bound stores overlap latency-bound top-k blocks; k_pre -> csx only.
//  * k_v merged into k_outn (k_nodeout): V row computed per-node into LDS
//    (+global for k_outt), identical fmaf order; one less launch.
//  * 4 kernels + 1 memset total.

constexpr int BS = 16, NN_ = 2048, CIN = 32, OUT = 64, TK = 10;
constexpr int ROWS = BS * NN_;

// ---------------- Threefry-2x32 (matches jax._src.prng) ----------------
__device__ __forceinline__ void tf2x32(unsigned x0, unsigned x1,
                                       unsigned& o0, unsigned& o1) {
  const unsigned k0 = 0u, k1 = 42u;
  const unsigned ks2 = k0 ^ k1 ^ 0x1BD11BDAu;
#define TF_R(rot) { x0 += x1; x1 = (x1 << rot) | (x1 >> (32 - rot)); x1 ^= x0; }
  x0 += k0; x1 += k1;
  TF_R(13) TF_R(15) TF_R(26) TF_R(6)
  x0 += k1; x1 += ks2 + 1u;
  TF_R(17) TF_R(29) TF_R(16) TF_R(24)
  x0 += ks2; x1 += k0 + 2u;
  TF_R(13) TF_R(15) TF_R(26) TF_R(6)
  x0 += k0; x1 += k1 + 3u;
  TF_R(17) TF_R(29) TF_R(16) TF_R(24)
  x0 += k1; x1 += ks2 + 4u;
  TF_R(13) TF_R(15) TF_R(26) TF_R(6)
  x0 += ks2; x1 += k0 + 5u;
#undef TF_R
  o0 = x0; o1 = x1;
}

__device__ __forceinline__ float noise_val(unsigned flat) {
  unsigned o0, o1; tf2x32(0u, flat, o0, o1);
  unsigned bits = o0 ^ o1;
  float u = __uint_as_float((bits >> 9) | 0x3f800000u) - 1.0f;
  return 0.01f * u;
}

// ---------------- K_csx: chunked colsum of x -> atomicAdd(double) ----------------
__global__ __launch_bounds__(256) void k_csx(const float* __restrict__ x,
                                             double* __restrict__ csxD) {
  const int b = blockIdx.x >> 4, ch = blockIdx.x & 15;   // 256 blocks
  const int c = threadIdx.x & 31, g = threadIdx.x >> 5;
  __shared__ double red[8][32];
  double acc = 0.0;
  for (int m = ch * 128 + g; m < ch * 128 + 128; m += 8)
    acc += (double)x[(((b << 11) + m) << 5) + c];
  red[g][c] = acc;
  __syncthreads();
  if (g == 0) {
    double s2 = red[0][c];
    #pragma unroll
    for (int i = 1; i < 8; ++i) s2 += red[i][c];
    atomicAdd(&csxD[(b << 5) + c], s2);
  }
}

// ---------------- K_topk: [Wn | Wt | A0-row + top-k + Y1 + csy] ----------------
// grid 2912: bid<768 -> Wn; bid<864 -> Wt; bid>=864 -> topk node (bid-864).
__global__ __launch_bounds__(256, 4) void k_topk(const float* __restrict__ ne,
                                                 const float* __restrict__ t,
                                                 const float* __restrict__ n_t,
                                                 const float* __restrict__ p,
                                                 const float* __restrict__ x,
                                                 const double* __restrict__ csxD,
                                                 const float* __restrict__ wp,
                                                 float* __restrict__ cinv,
                                                 int* __restrict__ idxb,
                                                 float* __restrict__ wgt,
                                                 float* __restrict__ Y1,
                                                 float* __restrict__ csy_part,
                                                 float* __restrict__ Wn,
                                                 float* __restrict__ Wt) {
  const int bid = blockIdx.x;
  const int warp = threadIdx.x >> 6, lane = threadIdx.x & 63;

  __shared__ float rowS[2048];                    // 8 KiB (neS alias in Wn branch)
  __shared__ float candA[4][128];
  __shared__ int   candM[4][128];
  __shared__ unsigned long long keyS[4][128];
  __shared__ int   winI[16][10];
  __shared__ float winW[16][10];
  __shared__ float ciS[16];

  if (bid < 768) {
    // ---- Wn branch: Wn[n][ki][o] = sum_d ne[n,d] wp[d,ki,o] ----
    float* neS = rowS;                            // [16*10]
    const int ng = bid / 6, sg = bid % 6;
    const int slot = sg * 256 + threadIdx.x;      // 96 ki x 16 o4
    const int ki = slot >> 4, o4 = slot & 15;

    if (threadIdx.x < 160)
      neS[threadIdx.x] = ne[ng * 160 + threadIdx.x];

    const float4* wp4 = (const float4*)wp;
    float4 w[10];
    #pragma unroll
    for (int d = 0; d < 10; ++d) w[d] = wp4[(d * 96 + ki) * 16 + o4];
    __syncthreads();

    float4* Wn4 = (float4*)Wn;
    #pragma unroll 4
    for (int nn = 0; nn < 16; ++nn) {
      float4 acc = {0.f, 0.f, 0.f, 0.f};
      #pragma unroll
      for (int d = 0; d < 10; ++d) {
        float e = neS[nn * 10 + d];
        acc.x = fmaf(e, w[d].x, acc.x); acc.y = fmaf(e, w[d].y, acc.y);
        acc.z = fmaf(e, w[d].z, acc.z); acc.w = fmaf(e, w[d].w, acc.w);
      }
      Wn4[((size_t)(ng * 16 + nn) * 96 + ki) * 16 + o4] = acc;
    }
    return;
  }
  if (bid < 864) {
    // ---- Wt branch: Wt[b][ki][o] = sum_d n_t[b,d] wp[10+d,ki,o] ----
    int gid = (bid - 768) * 256 + threadIdx.x;    // 24576 = 16*96*16
    int b = gid / 1536, rem = gid % 1536, ki = rem >> 4, o4 = rem & 15;
    const float4* wp4 = (const float4*)wp;
    float4 acc = {0.f, 0.f, 0.f, 0.f};
    #pragma unroll
    for (int d = 0; d < 8; ++d) {
      float e = n_t[b * 8 + d];
      float4 w = wp4[((10 + d) * 96 + ki) * 16 + o4];
      acc.x = fmaf(e, w.x, acc.x); acc.y = fmaf(e, w.y, acc.y);
      acc.z = fmaf(e, w.z, acc.z); acc.w = fmaf(e, w.w, acc.w);
    }
    ((float4*)Wt)[(b * 96 + ki) * 16 + o4] = acc;
    return;
  }

  // ================= top-k path (r11-verified) =================
  const int n = bid - 864;

  {
    float ner[10];
    #pragma unroll
    for (int d = 0; d < 10; ++d) ner[d] = ne[n * 10 + d];
    #pragma unroll
    for (int g2 = 0; g2 < 2; ++g2) {
      const int m0 = g2 * 1024 + threadIdx.x * 4;
      const float4* nf = (const float4*)(ne + (size_t)m0 * 10);
      float acc4[4] = {0.f, 0.f, 0.f, 0.f};
      #pragma unroll
      for (int i = 0; i < 10; ++i) {
        float4 q = nf[i];
        #pragma unroll
        for (int j = 0; j < 4; ++j) {
          const int e = i * 4 + j;
          const int rr = e / 10, d = e % 10;
          acc4[rr] = fmaf(ner[d], (&q.x)[j], acc4[rr]);
        }
      }
      *(float4*)&rowS[m0] = make_float4(acc4[0], acc4[1], acc4[2], acc4[3]);
    }
  }
  __syncthreads();                                // rowS complete (only barrier)

  float lm = -3.4e38f;
  #pragma unroll
  for (int j = 0; j < 8; ++j) {
    float4 f = ((const float4*)rowS)[j * 64 + lane];
    lm = fmaxf(lm, fmaxf(fmaxf(f.x, f.y), fmaxf(f.z, f.w)));
  }
  float last = 3.4e38f;
  for (int rd = 0; rd < 11; ++rd) {
    float x2 = (lm < last) ? lm : -3.4e38f;
    #pragma unroll
    for (int off = 32; off > 0; off >>= 1) x2 = fmaxf(x2, __shfl_xor(x2, off));
    last = x2;
  }
  const float T = last - 0.0101f;                 // a-space margin (s_b >= 1)

  int cnt = 0;
  #pragma unroll
  for (int slot = 0; slot < 32; ++slot) {
    float v = rowS[(slot >> 2) * 256 + lane * 4 + (slot & 3)];
    bool c = (v >= T);
    unsigned long long mk = __ballot(c);
    if (c) {
      int pos = cnt + __popcll(mk & ((1ull << lane) - 1ull));
      if (pos < 128) {
        candA[warp][pos] = v;
        candM[warp][pos] = ((slot >> 2) << 8) + (lane << 2) + (slot & 3);
      }
    }
    cnt += (int)__popcll(mk);
  }
  const int C = cnt < 128 ? cnt : 128;

  if (C <= 32) {
    // ---- FAST PATH: half-wave batch pairing ----
    const int h = lane >> 5, j = lane & 31;
    for (int pair = 0; pair < 2; ++pair) {
      const int b = warp * 4 + pair * 2 + h;
      const int r = (b << 11) | n;

      float at = 0.f;
      #pragma unroll
      for (int d = 0; d < 8; ++d) at = fmaf(n_t[b * 8 + d], t[b * 8 + d], at);
      const float s = 1.0f + 0.3f * (1.0f / (1.0f + expf(-p[b])));

      const bool act = (j < C);
      float pre = 0.f; int mj = 0;
      unsigned long long kk = 0ull;
      if (act) {
        float aj = candA[warp][j]; mj = candM[warp][j];
        pre = fmaxf(s * (aj + at), 0.f);
        float key = pre + noise_val((unsigned)r * 2048u + (unsigned)mj);
        kk = ((unsigned long long)__float_as_uint(key) << 32) |
             (unsigned)(2047 - mj);
      }
      keyS[warp][lane] = kk;

      int rank = 0;
      for (int j2 = 0; j2 < C; ++j2) {
        unsigned long long kj = keyS[warp][h * 32 + j2];
        rank += (kj > kk) ? 1 : 0;
      }
      const bool win = act && (rank < 10);

      float e = win ? expf(pre) : 0.f;
      float sum = e;
      #pragma unroll
      for (int off = 16; off > 0; off >>= 1) sum += __shfl_xor(sum, off);
      const float ci = 1.0f / (2038.0f + sum);

      unsigned long long mask = __ballot(win);
      unsigned mh = (unsigned)(mask >> (h * 32));
      if (win) {
        int pos = __popc(mh & ((1u << j) - 1u));
        idxb[r * 10 + pos] = mj;
        wgt[r * 10 + pos] = (e - 1.0f) * ci;
        winI[b][pos] = mj;
        winW[b][pos] = (e - 1.0f) * ci;
      }
      if (j == 0) { cinv[r] = ci; ciS[b] = ci; }
    }
  } else {
    // ---- FALLBACK (C in (32,128]): full-wave path ----
    const bool two = (C > 64);
    float a0c = 0.f, a1c = 0.f; int m0c = 0, m1c = 0;
    if (lane < C) { a0c = candA[warp][lane]; m0c = candM[warp][lane]; }
    if (two && lane + 64 < C) {
      a1c = candA[warp][lane + 64]; m1c = candM[warp][lane + 64];
    }
    for (int bi = 0; bi < 4; ++bi) {
      const int b = warp * 4 + bi;
      const int r = (b << 11) | n;

      float at = 0.f;
      #pragma unroll
      for (int d = 0; d < 8; ++d) at = fmaf(n_t[b * 8 + d], t[b * 8 + d], at);
      const float s = 1.0f + 0.3f * (1.0f / (1.0f + expf(-p[b])));

      float pre0 = fmaxf(s * (a0c + at), 0.f);
      unsigned long long k0 = 0ull;
      if (lane < C) {
        float key0 = pre0 + noise_val((unsigned)r * 2048u + (unsigned)m0c);
        k0 = ((unsigned long long)__float_as_uint(key0) << 32) |
             (unsigned)(2047 - m0c);
        keyS[warp][lane] = k0;
      }
      float pre1 = 0.f;
      unsigned long long k1 = 0ull;
      if (two) {
        if (lane + 64 < C) {
          pre1 = fmaxf(s * (a1c + at), 0.f);
          float key1 = pre1 + noise_val((unsigned)r * 2048u + (unsigned)m1c);
          k1 = ((unsigned long long)__float_as_uint(key1) << 32) |
               (unsigned)(2047 - m1c);
        }
        keyS[warp][lane + 64] = k1;
      }

      int rank0 = 0, rank1 = 0;
      for (int j2 = 0; j2 < C; ++j2) {
        unsigned long long kj = keyS[warp][j2];
        rank0 += (kj > k0) ? 1 : 0;
        if (two) rank1 += (kj > k1) ? 1 : 0;
      }
      bool w0 = (lane < C) && (rank0 < 10);
      bool w1 = two && (lane + 64 < C) && (rank1 < 10);

      float e0 = w0 ? expf(pre0) : 0.f;
      float e1 = w1 ? expf(pre1) : 0.f;
      float sum = e0 + e1;
      #pragma unroll
      for (int off = 32; off > 0; off >>= 1) sum += __shfl_xor(sum, off);
      const float ci = 1.0f / (2038.0f + sum);

      unsigned long long mk0 = __ballot(w0);
      if (w0) {
        int pos = __popcll(mk0 & ((1ull << lane) - 1ull));
        idxb[r * 10 + pos] = m0c;
        wgt[r * 10 + pos] = (e0 - 1.0f) * ci;
        winI[b][pos] = m0c;
        winW[b][pos] = (e0 - 1.0f) * ci;
      }
      if (two) {
        unsigned long long mk1 = __ballot(w1);
        int base = __popcll(mk0);
        if (w1) {
          int pos = base + __popcll(mk1 & ((1ull << lane) - 1ull));
          idxb[r * 10 + pos] = m1c;
          wgt[r * 10 + pos] = (e1 - 1.0f) * ci;
          winI[b][pos] = m1c;
          winW[b][pos] = (e1 - 1.0f) * ci;
        }
      }
      if (lane == 0) { cinv[r] = ci; ciS[b] = ci; }
    }
  }

  // ---- Y1 phase (fused axpy): 2 passes x (2 rows x 32 cols) per warp ----
  #pragma unroll
  for (int pass = 0; pass < 2; ++pass) {
    const int bi2 = pass * 2 + (lane >> 5);
    const int b = warp * 4 + bi2;
    const int c = lane & 31;
    const int r = (b << 11) | n;
    float acc = ciS[b] * (float)csxD[(b << 5) + c];
    #pragma unroll
    for (int j = 0; j < 10; ++j) {
      int m = winI[b][j];
      float w = winW[b][j];
      acc = fmaf(w, x[(((b << 11) + m) << 5) + c], acc);
    }
    Y1[(size_t)r * 32 + c] = acc;
    atomicAdd(&csy_part[((n & 7) << 9) + (b << 5) + c], acc);
  }
}

// ---------------- K_nodeout: V rows (k_v) + node-term + bias (1 node/block) ----------------
__global__ __launch_bounds__(256) void k_nodeout(const float* __restrict__ ne,
                                                 const float* __restrict__ n_t,
                                                 const float* __restrict__ Wn,
                                                 const float* __restrict__ bp,
                                                 const float* __restrict__ x,
                                                 const float* __restrict__ Y1,
                                                 const float* __restrict__ cinv,
                                                 const int* __restrict__ idxb,
                                                 const float* __restrict__ wgt,
                                                 const float* __restrict__ csy_part,
                                                 float* __restrict__ V,
                                                 float* __restrict__ out) {
  const int n = blockIdx.x;                     // 2048 blocks
  __shared__ float Vs[16][100];
  __shared__ float bNs[64];

  // ---- phase A: V rows for node n (identical math/order to old k_v) ----
  {
    const int b = threadIdx.x >> 4, c2 = threadIdx.x & 15;
    const int r = (b << 11) | n;
    const float ci = cinv[r];
    int mj[10]; float wj[10];
    #pragma unroll
    for (int j = 0; j < 10; ++j) {
      mj[j] = idxb[r * 10 + j];
      wj[j] = wgt[r * 10 + j];
    }
    #pragma unroll
    for (int cc = 0; cc < 2; ++cc) {
      const int c = c2 + cc * 16;
      float cs = 0.f;
      #pragma unroll
      for (int k = 0; k < 8; ++k) cs += csy_part[(k << 9) + (b << 5) + c];
      float y2 = ci * cs;
      #pragma unroll
      for (int j = 0; j < 10; ++j)
        y2 = fmaf(wj[j], Y1[(((b << 11) + mj[j]) << 5) + c], y2);
      float xv = x[((size_t)r << 5) + c];
      float y1v = Y1[((size_t)r << 5) + c];
      float ch2 = 2.f * y2 - xv;
      Vs[b][c] = xv; Vs[b][32 + c] = y1v; Vs[b][64 + c] = ch2;
      V[(size_t)r * 96 + c] = xv;
      V[(size_t)r * 96 + 32 + c] = y1v;
      V[(size_t)r * 96 + 64 + c] = ch2;
    }
  }
  if (threadIdx.x < 64) {
    float acc = 0.f;
    #pragma unroll
    for (int d = 0; d < 10; ++d)
      acc = fmaf(ne[n * 10 + d], bp[d * 64 + threadIdx.x], acc);
    bNs[threadIdx.x] = acc;
  }
  __syncthreads();

  // ---- phase B: node-term, streaming Wn (r11-verified) ----
  const int b = threadIdx.x >> 4, og = threadIdx.x & 15;
  const float4* Wr = (const float4*)(Wn + (size_t)n * 6144);

  float4 acc = {0.f, 0.f, 0.f, 0.f};
  #pragma unroll 4
  for (int ki = 0; ki < 96; ++ki) {
    float4 wv = Wr[ki * 16 + og];
    float v = Vs[b][ki];
    acc.x = fmaf(v, wv.x, acc.x); acc.y = fmaf(v, wv.y, acc.y);
    acc.z = fmaf(v, wv.z, acc.z); acc.w = fmaf(v, wv.w, acc.w);
  }

  float4 res;
  #pragma unroll
  for (int q = 0; q < 4; ++q) {
    int o = og * 4 + q;
    float bT = 0.f;
    #pragma unroll
    for (int d = 0; d < 8; ++d)
      bT = fmaf(n_t[b * 8 + d], bp[(10 + d) * 64 + o], bT);
    (&res.x)[q] = (&acc.x)[q] + bNs[o] + bT;
  }
  *(float4*)&out[((size_t)(b << 11) + n) * 64 + og * 4] = res;
}

// ---------------- K_outt: out += V @ Wt[b] (Wt precomputed) ----------------
__global__ __launch_bounds__(512) void k_outt(const float* __restrict__ WtG,
                                              const float* __restrict__ V,
                                              float* __restrict__ out) {
  const int b = blockIdx.x >> 5, tile = blockIdx.x & 31;   // 512 blocks
  __shared__ float Wt[96][64];
  {
    const float4* src = (const float4*)(WtG + (size_t)b * 6144);
    float4* dst = (float4*)Wt;
    for (int e = threadIdx.x; e < 1536; e += 512) dst[e] = src[e];
  }
  __syncthreads();
  const int wave = threadIdx.x >> 6, lane = threadIdx.x & 63;
  const int og = lane & 15, rg = lane >> 4;
  const int r0 = tile * 64 + wave * 8 + rg * 2;

  float acc[2][4] = {};
  for (int ki4 = 0; ki4 < 24; ++ki4) {
    float4 vv[2];
    #pragma unroll
    for (int i = 0; i < 2; ++i)
      vv[i] = *(const float4*)&V[(size_t)((b << 11) + r0 + i) * 96 + ki4 * 4];
    #pragma unroll
    for (int t2 = 0; t2 < 4; ++t2) {
      float4 wv = *(const float4*)&Wt[ki4 * 4 + t2][og * 4];
      #pragma unroll
      for (int i = 0; i < 2; ++i) {
        float vi = (t2 == 0) ? vv[i].x : (t2 == 1) ? vv[i].y
                 : (t2 == 2) ? vv[i].z : vv[i].w;
        acc[i][0] = fmaf(vi, wv.x, acc[i][0]);
        acc[i][1] = fmaf(vi, wv.y, acc[i][1]);
        acc[i][2] = fmaf(vi, wv.z, acc[i][2]);
        acc[i][3] = fmaf(vi, wv.w, acc[i][3]);
      }
    }
  }
  #pragma unroll
  for (int i = 0; i < 2; ++i) {
    size_t oidx = (size_t)((b << 11) + r0 + i) * 64 + og * 4;
    float4 cur = *(float4*)&out[oidx];
    cur.x += acc[i][0]; cur.y += acc[i][1];
    cur.z += acc[i][2]; cur.w += acc[i][3];
    *(float4*)&out[oidx] = cur;
  }
}

extern "C" void kernel_launch(void* const* d_in, const int* in_sizes, int n_in,
                              void* d_out, int out_size, void* d_ws, size_t ws_size,
                              hipStream_t stream) {
  const float* x   = (const float*)d_in[0];
  const float* ne  = (const float*)d_in[1];
  const float* t   = (const float*)d_in[2];
  const float* n_t = (const float*)d_in[3];
  const float* p   = (const float*)d_in[4];
  const float* wp  = (const float*)d_in[5];
  const float* bp  = (const float*)d_in[6];
  float* out = (float*)d_out;
  float* ws = (float*)d_ws;
  (void)in_sizes; (void)n_in; (void)out_size; (void)ws_size;

  // layout (floats; ws is 268 MB). csxD 8B-aligned.
  float* cinv     = ws;                         // 32,768
  int*   idxb     = (int*)(cinv + 32768);       // 327,680
  float* wgt      = (float*)(idxb + 327680);    // 327,680
  double* csxD    = (double*)(wgt + 327680);    // 512 doubles
  float* csy_part = (float*)(csxD + 512);       // 4,096 (8 partials x 512)
  float* Y1       = csy_part + 4096;            // 1,048,576
  float* V        = Y1 + 1048576;               // 3,145,728
  float* Wt       = V + 3145728;                // 98,304
  float* Wn       = Wt + 98304;                 // 12,582,912

  // zero csxD (4 KB) + csy_part (16 KB): one capture-safe memset node
  hipMemsetAsync(csxD, 0, 512 * 8 + 4096 * 4, stream);

  k_csx    <<<256, 256, 0, stream>>>(x, csxD);
  k_topk   <<<2912, 256, 0, stream>>>(ne, t, n_t, p, x, csxD, wp,
                                      cinv, idxb, wgt, Y1, csy_part, Wn, Wt);
  k_nodeout<<<2048, 256, 0, stream>>>(ne, n_t, Wn, bp, x, Y1,
                                      cinv, idxb, wgt, csy_part, V, out);
  k_outt   <<<512, 512, 0, stream>>>(Wt, V, out);
}